// Round 7
// baseline (421.834 us; speedup 1.0000x reference)
//
#include <hip/hip_runtime.h>
#include <hip/hip_bf16.h>

typedef short bf16x8 __attribute__((ext_vector_type(8)));
typedef float f32x4 __attribute__((ext_vector_type(4)));
#define MFMA16 __builtin_amdgcn_mfma_f32_16x16x32_bf16

// ---- split-bf16 helpers -----------------------------------------------------
__device__ __forceinline__ unsigned short rne_bf16(float f) {
  unsigned u = __builtin_bit_cast(unsigned, f);
  return (unsigned short)((u + 0x7fffu + ((u >> 16) & 1u)) >> 16);
}
__device__ __forceinline__ float bf16f(unsigned short h) {
  unsigned u = ((unsigned)h) << 16;
  return __builtin_bit_cast(float, u);
}
__device__ __forceinline__ void split2(float f, short& h, short& l) {
  unsigned short hh = rne_bf16(f);
  h = (short)hh;
  l = (short)rne_bf16(f - bf16f(hh));
}

// ---- ws layout --------------------------------------------------------------
constexpr int NW_SH = 32768;   // node_W  256x128
constexpr int WC_SH = 16384;   // WcEt    128x128
constexpr int GF_SH = 65536;   // gfcn    128x512
constexpr int OFF_NWH = 0;
constexpr int OFF_NWL = NW_SH;
constexpr int OFF_WCH = 2 * NW_SH;
constexpr int OFF_WCL = 2 * NW_SH + WC_SH;
constexpr int OFF_GFH = 2 * NW_SH + 2 * WC_SH;
constexpr int OFF_GFL = 2 * NW_SH + 2 * WC_SH + GF_SH;
constexpr size_t OFF_BIAS_BYTES = (size_t)(2 * NW_SH + 2 * WC_SH + 2 * GF_SH) * 2; // 458752
constexpr size_t OFF_VF_BYTES = OFF_BIAS_BYTES + 6 * 128 * 4;                      // 461824
constexpr int NT_MAX = 2048;                    // B/16
constexpr int VF_SH = NT_MAX * 4 * 4 * 64 * 8;  // 16777216 shorts per plane
constexpr size_t WS_NEED = OFF_VF_BYTES + (size_t)2 * (size_t)VF_SH * 2;           // ~67.6 MB

// ---- setup: pack weights into MFMA fragment layout (hi/lo bf16 planes) ------
__global__ __launch_bounds__(256) void setup_kernel(
    const float* __restrict__ node_W, const float* __restrict__ conv_W,
    const float* __restrict__ gfcn_W, const float* __restrict__ role_emb,
    const float* __restrict__ conv_b, const float* __restrict__ bn_gamma,
    const float* __restrict__ bn_beta, const float* __restrict__ bn_mean,
    const float* __restrict__ bn_var, short* __restrict__ wsS,
    float* __restrict__ bias_af) {
  int idx = blockIdx.x * 256 + threadIdx.x;
  int stride = gridDim.x * 256;
  for (int i = idx; i < 115456; i += stride) {
    if (i < 114688) {
      int j = i & 7, lane = (i >> 3) & 63;
      int kq = ((lane >> 4) & 3) * 8 + j, n16 = lane & 15;
      float val;
      short *ph, *pl;
      int loc;
      if (i < NW_SH) {
        loc = i;
        int f = i >> 9, kf = f & 7, nfr = f >> 3;
        int k = kf * 32 + kq, n = nfr * 16 + n16;
        val = node_W[k * 128 + n];
        ph = wsS + OFF_NWH; pl = wsS + OFF_NWL;
      } else if (i < NW_SH + WC_SH) {
        loc = i - NW_SH;
        int f = loc >> 9, kf = f & 3, nfr = f >> 2;
        int k = kf * 32 + kq, n = nfr * 16 + n16;
        float s = bn_gamma[n] * rsqrtf(bn_var[n] + 1e-5f);
        val = s * conv_W[n * 256 + 128 + k];     // WcEt[e=k][f=n]
        ph = wsS + OFF_WCH; pl = wsS + OFF_WCL;
      } else {
        loc = i - NW_SH - WC_SH;
        int f = loc >> 9, kf = f & 3, nfr = f >> 2;   // nfr 0..31
        int k = kf * 32 + kq, n = nfr * 16 + n16;     // n 0..511
        val = (n < 256) ? gfcn_W[k * 256 + n]
                        : gfcn_W[(128 + k) * 256 + (n - 256)];
        ph = wsS + OFF_GFH; pl = wsS + OFF_GFL;
      }
      short h, l;
      split2(val, h, l);
      ph[loc] = h; pl[loc] = l;
    } else {
      int loc = i - 114688;
      int a = loc >> 7, fc = loc & 127;
      int role = (a == 5) ? 6 : a;   // ROLES = {0,1,2,3,4,6}
      float s = bn_gamma[fc] * rsqrtf(bn_var[fc] + 1e-5f);
      float dot = 0.f;
      for (int e = 0; e < 128; ++e)
        dot = fmaf(role_emb[role * 128 + e], conv_W[fc * 256 + e], dot);
      bias_af[loc] = s * (dot + conv_b[fc] - bn_mean[fc]) + bn_beta[fc];
    }
  }
}

// ---- kernel A: vals[a] = entity + relu(nf@node_W + node_b) -> ws A-frags ----
__global__ __launch_bounds__(256) void ent_kernel(
    const int* __restrict__ a_ids, const int* __restrict__ b_ids,
    const int* __restrict__ c_ids, const int* __restrict__ event_ids,
    const float* __restrict__ nf, const float* __restrict__ ent,
    const float* __restrict__ node_b, const short* __restrict__ wsS,
    short* __restrict__ vfh, short* __restrict__ vfl) {
  __shared__ __align__(16) short lhs[64 * 128];
  __shared__ __align__(16) short lls[64 * 128];
  const int t = threadIdx.x;
  const int wv = t >> 6, lane = t & 63;
  const int r15 = lane & 15, q = lane >> 4;
  const int tile = blockIdx.x;
  const int b0 = tile * 16;

  const bf16x8* nwh = (const bf16x8*)(wsS + OFF_NWH);
  const bf16x8* nwl = (const bf16x8*)(wsS + OFF_NWL);

  // wave wv owns id-column wv; stack order a,event,b,c
  const int* pw = (wv == 0) ? a_ids : (wv == 1) ? event_ids
                : (wv == 2) ? b_ids : c_ids;
  int my_id = pw[b0 + r15];
  int eid[4];
  #pragma unroll
  for (int rg = 0; rg < 4; ++rg) eid[rg] = pw[b0 + q * 4 + rg];
  const float* arow = nf + (size_t)my_id * 256 + q * 8;

  float4 avA[8];
  #pragma unroll
  for (int ks = 0; ks < 4; ++ks) {
    avA[2 * ks]     = *(const float4*)(arow + ks * 32);
    avA[2 * ks + 1] = *(const float4*)(arow + ks * 32 + 4);
  }

  f32x4 acc[8];
  #pragma unroll
  for (int n8 = 0; n8 < 8; ++n8) acc[n8] = (f32x4){0.f, 0.f, 0.f, 0.f};
  float4 avB[8];
  #pragma unroll
  for (int ks = 0; ks < 4; ++ks) {
    avB[2 * ks]     = *(const float4*)(arow + (4 + ks) * 32);
    avB[2 * ks + 1] = *(const float4*)(arow + (4 + ks) * 32 + 4);
  }
  #pragma unroll
  for (int ks = 0; ks < 8; ++ks) {
    bf16x8 ah, al;
    {
      float4 v0 = (ks < 4) ? avA[2 * ks] : avB[2 * (ks - 4)];
      float4 v1 = (ks < 4) ? avA[2 * ks + 1] : avB[2 * (ks - 4) + 1];
      #pragma unroll
      for (int j = 0; j < 4; ++j) {
        short h, l;
        split2(v0[j], h, l);
        ah[j] = h; al[j] = l;
        split2(v1[j], h, l);
        ah[4 + j] = h; al[4 + j] = l;
      }
    }
    #pragma unroll
    for (int n8 = 0; n8 < 8; ++n8) {
      bf16x8 bh = nwh[(n8 * 8 + ks) * 64 + lane];
      bf16x8 bl = nwl[(n8 * 8 + ks) * 64 + lane];
      acc[n8] = MFMA16(ah, bh, acc[n8], 0, 0, 0);
      acc[n8] = MFMA16(al, bh, acc[n8], 0, 0, 0);
      acc[n8] = MFMA16(ah, bl, acc[n8], 0, 0, 0);
    }
  }
  // hoisted ent gather
  float ev[32];
  #pragma unroll
  for (int n8 = 0; n8 < 8; ++n8)
    #pragma unroll
    for (int rg = 0; rg < 4; ++rg)
      ev[n8 * 4 + rg] = ent[(size_t)eid[rg] * 128 + n8 * 16 + r15];
  #pragma unroll
  for (int n8 = 0; n8 < 8; ++n8) {
    int col = n8 * 16 + r15;
    float nb = node_b[col];
    #pragma unroll
    for (int rg = 0; rg < 4; ++rg) {
      float v = ev[n8 * 4 + rg] + fmaxf(acc[n8][rg] + nb, 0.f);
      short h, l; split2(v, h, l);
      int row = wv * 16 + q * 4 + rg;
      int si = row * 128 + (col ^ ((row & 7) << 3));
      lhs[si] = h; lls[si] = l;
    }
  }
  __syncthreads();
  // frag-layout read, coalesced ws store
  #pragma unroll
  for (int ks = 0; ks < 4; ++ks) {
    int row = wv * 16 + r15;
    int k0 = ks * 32 + q * 8;
    int si = row * 128 + (k0 ^ ((row & 7) << 3));
    ((bf16x8*)vfh)[((tile * 4 + wv) * 4 + ks) * 64 + lane] = *(const bf16x8*)&lhs[si];
    ((bf16x8*)vfl)[((tile * 4 + wv) * 4 + ks) * 64 + lane] = *(const bf16x8*)&lls[si];
  }
}

// ---- kernel B: stages C+D, 3 blocks/CU --------------------------------------
__global__ __launch_bounds__(256, 3) void head_kernel(
    const float* __restrict__ cond, const float* __restrict__ text,
    const float* __restrict__ gfcn_b, const short* __restrict__ wsS,
    const float* __restrict__ bias_af, const short* __restrict__ vfh,
    const short* __restrict__ vfl, float* __restrict__ out) {
  __shared__ __align__(16) unsigned char smem[49152];
  short* lds_hi = (short*)smem;                 // 96x128 bf16 hi plane
  short* lds_lo = (short*)(smem + 24576);       // lo plane
  float* umin_s = (float*)smem;                 // overlay after planes dead
  float* vmin_s = (float*)(smem + 16640);       // stride 260 floats
  constexpr int OV = 260;

  const int t = threadIdx.x;
  const int wv = t >> 6, lane = t & 63;
  const int r15 = lane & 15, q = lane >> 4;
  const int tile = blockIdx.x;
  const int b0 = tile * 16;

  const bf16x8* wch = (const bf16x8*)(wsS + OFF_WCH);
  const bf16x8* wcl = (const bf16x8*)(wsS + OFF_WCL);
  const bf16x8* gfh = (const bf16x8*)(wsS + OFF_GFH);
  const bf16x8* gfl = (const bf16x8*)(wsS + OFF_GFL);
  const bf16x8* vfh8 = (const bf16x8*)vfh;
  const bf16x8* vfl8 = (const bf16x8*)vfl;

  // ---- Phase 0: stage cond/text rows (a=4,5) into plane rows 64..95 ---------
  #pragma unroll
  for (int j = 0; j < 16; ++j) {
    int i = j * 256 + t;
    int arr = i >> 11, rem = i & 2047, r = rem >> 7, e = rem & 127;
    const float* src = arr ? text : cond;
    float v = src[(size_t)(b0 + r) * 128 + e];
    short h, l;
    split2(v, h, l);
    int row = (4 + arr) * 16 + r;
    int si = row * 128 + (e ^ ((row & 7) << 3));
    lds_hi[si] = h; lds_lo[si] = l;
  }
  __syncthreads();

  // ---- Stage C: x = relu(vals @ WcEt + bias_af) -----------------------------
  {
    f32x4 xacc[6][2];
    #pragma unroll
    for (int a = 0; a < 6; ++a) {
      xacc[a][0] = (f32x4){0.f, 0.f, 0.f, 0.f};
      xacc[a][1] = (f32x4){0.f, 0.f, 0.f, 0.f};
    }
    #pragma unroll
    for (int ks = 0; ks < 4; ++ks) {
      int k0 = ks * 32 + q * 8;
      #pragma unroll
      for (int ha = 0; ha < 2; ++ha) {
        bf16x8 ah[3], al[3];
        #pragma unroll
        for (int j = 0; j < 3; ++j) {
          int a = ha * 3 + j;
          if (a < 4) {
            ah[j] = vfh8[((tile * 4 + a) * 4 + ks) * 64 + lane];
            al[j] = vfl8[((tile * 4 + a) * 4 + ks) * 64 + lane];
          } else {
            int row = a * 16 + r15;
            int si = row * 128 + (k0 ^ ((row & 7) << 3));
            ah[j] = *(const bf16x8*)&lds_hi[si];
            al[j] = *(const bf16x8*)&lds_lo[si];
          }
        }
        #pragma unroll
        for (int jn = 0; jn < 2; ++jn) {
          bf16x8 bh = wch[((wv * 2 + jn) * 4 + ks) * 64 + lane];
          bf16x8 bl = wcl[((wv * 2 + jn) * 4 + ks) * 64 + lane];
          #pragma unroll
          for (int j = 0; j < 3; ++j) {
            int a = ha * 3 + j;
            xacc[a][jn] = MFMA16(ah[j], bh, xacc[a][jn], 0, 0, 0);
            xacc[a][jn] = MFMA16(al[j], bh, xacc[a][jn], 0, 0, 0);
            xacc[a][jn] = MFMA16(ah[j], bl, xacc[a][jn], 0, 0, 0);
          }
        }
      }
    }
    __syncthreads();   // all cond/text plane reads done before x overwrites
    #pragma unroll
    for (int a = 0; a < 6; ++a) {
      #pragma unroll
      for (int jn = 0; jn < 2; ++jn) {
        int col = (wv * 2 + jn) * 16 + r15;
        float bv = bias_af[a * 128 + col];
        #pragma unroll
        for (int rg = 0; rg < 4; ++rg) {
          float v = fmaxf(xacc[a][jn][rg] + bv, 0.f);
          short h, l; split2(v, h, l);
          int row = a * 16 + q * 4 + rg;
          int si = row * 128 + (col ^ ((row & 7) << 3));
          lds_hi[si] = h; lds_lo[si] = l;
        }
      }
    }
  }
  __syncthreads();

  // ---- Stage D: u/v = x @ gfcn, min over a; 4 grps x 2 jn; 3-a A-batches ----
  f32x4 mreg[8];
  #pragma unroll
  for (int grp = 0; grp < 4; ++grp) {
    f32x4 acc[6][2];
    #pragma unroll
    for (int a = 0; a < 6; ++a) {
      acc[a][0] = (f32x4){0.f, 0.f, 0.f, 0.f};
      acc[a][1] = (f32x4){0.f, 0.f, 0.f, 0.f};
    }
    #pragma unroll
    for (int ks = 0; ks < 4; ++ks) {
      int k0 = ks * 32 + q * 8;
      #pragma unroll
      for (int ha = 0; ha < 2; ++ha) {
        bf16x8 ah[3], al[3];
        #pragma unroll
        for (int j = 0; j < 3; ++j) {
          int row = (ha * 3 + j) * 16 + r15;
          int si = row * 128 + (k0 ^ ((row & 7) << 3));
          ah[j] = *(const bf16x8*)&lds_hi[si];
          al[j] = *(const bf16x8*)&lds_lo[si];
        }
        #pragma unroll
        for (int jn = 0; jn < 2; ++jn) {
          int nfg = wv * 8 + grp * 2 + jn;
          bf16x8 bh = gfh[(nfg * 4 + ks) * 64 + lane];
          bf16x8 bl = gfl[(nfg * 4 + ks) * 64 + lane];
          #pragma unroll
          for (int j = 0; j < 3; ++j) {
            int a = ha * 3 + j;
            acc[a][jn] = MFMA16(ah[j], bh, acc[a][jn], 0, 0, 0);
            acc[a][jn] = MFMA16(al[j], bh, acc[a][jn], 0, 0, 0);
            acc[a][jn] = MFMA16(ah[j], bl, acc[a][jn], 0, 0, 0);
          }
        }
      }
    }
    #pragma unroll
    for (int jn = 0; jn < 2; ++jn) {
      #pragma unroll
      for (int rg = 0; rg < 4; ++rg) {
        float mm = acc[0][jn][rg];
        #pragma unroll
        for (int a = 1; a < 6; ++a) mm = fminf(mm, acc[a][jn][rg]);
        mreg[grp * 2 + jn][rg] = mm;
      }
    }
  }
  __syncthreads();   // all x reads done; planes now dead
  {
    float* dst = (wv >= 2) ? vmin_s : umin_s;
    int cbase = (wv & 1) * 128;
    #pragma unroll
    for (int j = 0; j < 8; ++j) {
      int colg = cbase + j * 16 + r15;
      #pragma unroll
      for (int rg = 0; rg < 4; ++rg)
        dst[(q * 4 + rg) * OV + colg] = mreg[j][rg];
    }
  }
  __syncthreads();
  #pragma unroll
  for (int j = 0; j < 16; ++j) {
    int i = j * 256 + t;
    int r = i >> 8, g = i & 255;
    out[(size_t)(b0 + r) * 256 + g] =
        fmaxf(umin_s[r * OV + g] + vmin_s[r * OV + g] + gfcn_b[g], 0.f);
  }
}

// ---- fallback: fused (R5 structure, no min-wave bound) ----------------------
__global__ __launch_bounds__(256) void fused_fallback(
    const int* __restrict__ a_ids, const int* __restrict__ b_ids,
    const int* __restrict__ c_ids, const int* __restrict__ event_ids,
    const float* __restrict__ nf, const float* __restrict__ cond,
    const float* __restrict__ text, const float* __restrict__ ent,
    const float* __restrict__ node_b, const float* __restrict__ gfcn_b,
    const short* __restrict__ wsS, const float* __restrict__ bias_af,
    float* __restrict__ out) {
  __shared__ __align__(16) unsigned char smem[49152];
  short* lds_hi = (short*)smem;
  short* lds_lo = (short*)(smem + 24576);
  float* umin_s = (float*)smem;
  float* vmin_s = (float*)(smem + 16640);
  constexpr int OV = 260;

  const int t = threadIdx.x;
  const int wv = t >> 6, lane = t & 63;
  const int r15 = lane & 15, q = lane >> 4;
  const int b0 = blockIdx.x * 16;

  const bf16x8* nwh = (const bf16x8*)(wsS + OFF_NWH);
  const bf16x8* nwl = (const bf16x8*)(wsS + OFF_NWL);
  const bf16x8* wch = (const bf16x8*)(wsS + OFF_WCH);
  const bf16x8* wcl = (const bf16x8*)(wsS + OFF_WCL);
  const bf16x8* gfh = (const bf16x8*)(wsS + OFF_GFH);
  const bf16x8* gfl = (const bf16x8*)(wsS + OFF_GFL);

  const int* pw = (wv == 0) ? a_ids : (wv == 1) ? event_ids
                : (wv == 2) ? b_ids : c_ids;
  int my_id = pw[b0 + r15];
  int eid[4];
  #pragma unroll
  for (int rg = 0; rg < 4; ++rg) eid[rg] = pw[b0 + q * 4 + rg];
  const float* arow = nf + (size_t)my_id * 256 + q * 8;

  float4 avA[8];
  #pragma unroll
  for (int ks = 0; ks < 4; ++ks) {
    avA[2 * ks]     = *(const float4*)(arow + ks * 32);
    avA[2 * ks + 1] = *(const float4*)(arow + ks * 32 + 4);
  }
  #pragma unroll
  for (int j = 0; j < 16; ++j) {
    int i = j * 256 + t;
    int arr = i >> 11, rem = i & 2047, r = rem >> 7, e = rem & 127;
    const float* src = arr ? text : cond;
    float v = src[(size_t)(b0 + r) * 128 + e];
    short h, l;
    split2(v, h, l);
    int row = (4 + arr) * 16 + r;
    int si = row * 128 + (e ^ ((row & 7) << 3));
    lds_hi[si] = h; lds_lo[si] = l;
  }
  {
    f32x4 acc[8];
    #pragma unroll
    for (int n8 = 0; n8 < 8; ++n8) acc[n8] = (f32x4){0.f, 0.f, 0.f, 0.f};
    float4 avB[8];
    #pragma unroll
    for (int ks = 0; ks < 4; ++ks) {
      avB[2 * ks]     = *(const float4*)(arow + (4 + ks) * 32);
      avB[2 * ks + 1] = *(const float4*)(arow + (4 + ks) * 32 + 4);
    }
    #pragma unroll
    for (int ks = 0; ks < 8; ++ks) {
      bf16x8 ah, al;
      {
        float4 v0 = (ks < 4) ? avA[2 * ks] : avB[2 * (ks - 4)];
        float4 v1 = (ks < 4) ? avA[2 * ks + 1] : avB[2 * (ks - 4) + 1];
        #pragma unroll
        for (int j = 0; j < 4; ++j) {
          short h, l;
          split2(v0[j], h, l);
          ah[j] = h; al[j] = l;
          split2(v1[j], h, l);
          ah[4 + j] = h; al[4 + j] = l;
        }
      }
      #pragma unroll
      for (int n8 = 0; n8 < 8; ++n8) {
        bf16x8 bh = nwh[(n8 * 8 + ks) * 64 + lane];
        bf16x8 bl = nwl[(n8 * 8 + ks) * 64 + lane];
        acc[n8] = MFMA16(ah, bh, acc[n8], 0, 0, 0);
        acc[n8] = MFMA16(al, bh, acc[n8], 0, 0, 0);
        acc[n8] = MFMA16(ah, bl, acc[n8], 0, 0, 0);
      }
    }
    float ev[32];
    #pragma unroll
    for (int n8 = 0; n8 < 8; ++n8)
      #pragma unroll
      for (int rg = 0; rg < 4; ++rg)
        ev[n8 * 4 + rg] = ent[(size_t)eid[rg] * 128 + n8 * 16 + r15];
    #pragma unroll
    for (int n8 = 0; n8 < 8; ++n8) {
      int col = n8 * 16 + r15;
      float nb = node_b[col];
      #pragma unroll
      for (int rg = 0; rg < 4; ++rg) {
        float v = ev[n8 * 4 + rg] + fmaxf(acc[n8][rg] + nb, 0.f);
        short h, l; split2(v, h, l);
        int row = wv * 16 + q * 4 + rg;
        int si = row * 128 + (col ^ ((row & 7) << 3));
        lds_hi[si] = h; lds_lo[si] = l;
      }
    }
  }
  __syncthreads();
  {
    f32x4 xacc[6][2];
    #pragma unroll
    for (int a = 0; a < 6; ++a) {
      xacc[a][0] = (f32x4){0.f, 0.f, 0.f, 0.f};
      xacc[a][1] = (f32x4){0.f, 0.f, 0.f, 0.f};
    }
    #pragma unroll
    for (int ks = 0; ks < 4; ++ks) {
      int k0 = ks * 32 + q * 8;
      #pragma unroll
      for (int ha = 0; ha < 2; ++ha) {
        bf16x8 ah[3], al[3];
        #pragma unroll
        for (int j = 0; j < 3; ++j) {
          int row = (ha * 3 + j) * 16 + r15;
          int si = row * 128 + (k0 ^ ((row & 7) << 3));
          ah[j] = *(const bf16x8*)&lds_hi[si];
          al[j] = *(const bf16x8*)&lds_lo[si];
        }
        #pragma unroll
        for (int jn = 0; jn < 2; ++jn) {
          bf16x8 bh = wch[((wv * 2 + jn) * 4 + ks) * 64 + lane];
          bf16x8 bl = wcl[((wv * 2 + jn) * 4 + ks) * 64 + lane];
          #pragma unroll
          for (int j = 0; j < 3; ++j) {
            int a = ha * 3 + j;
            xacc[a][jn] = MFMA16(ah[j], bh, xacc[a][jn], 0, 0, 0);
            xacc[a][jn] = MFMA16(al[j], bh, xacc[a][jn], 0, 0, 0);
            xacc[a][jn] = MFMA16(ah[j], bl, xacc[a][jn], 0, 0, 0);
          }
        }
      }
    }
    __syncthreads();
    #pragma unroll
    for (int a = 0; a < 6; ++a) {
      #pragma unroll
      for (int jn = 0; jn < 2; ++jn) {
        int col = (wv * 2 + jn) * 16 + r15;
        float bv = bias_af[a * 128 + col];
        #pragma unroll
        for (int rg = 0; rg < 4; ++rg) {
          float v = fmaxf(xacc[a][jn][rg] + bv, 0.f);
          short h, l; split2(v, h, l);
          int row = a * 16 + q * 4 + rg;
          int si = row * 128 + (col ^ ((row & 7) << 3));
          lds_hi[si] = h; lds_lo[si] = l;
        }
      }
    }
  }
  __syncthreads();
  f32x4 mreg[8];
  #pragma unroll
  for (int grp = 0; grp < 4; ++grp) {
    f32x4 acc[6][2];
    #pragma unroll
    for (int a = 0; a < 6; ++a) {
      acc[a][0] = (f32x4){0.f, 0.f, 0.f, 0.f};
      acc[a][1] = (f32x4){0.f, 0.f, 0.f, 0.f};
    }
    #pragma unroll
    for (int ks = 0; ks < 4; ++ks) {
      int k0 = ks * 32 + q * 8;
      #pragma unroll
      for (int ha = 0; ha < 2; ++ha) {
        bf16x8 ah[3], al[3];
        #pragma unroll
        for (int j = 0; j < 3; ++j) {
          int row = (ha * 3 + j) * 16 + r15;
          int si = row * 128 + (k0 ^ ((row & 7) << 3));
          ah[j] = *(const bf16x8*)&lds_hi[si];
          al[j] = *(const bf16x8*)&lds_lo[si];
        }
        #pragma unroll
        for (int jn = 0; jn < 2; ++jn) {
          int nfg = wv * 8 + grp * 2 + jn;
          bf16x8 bh = gfh[(nfg * 4 + ks) * 64 + lane];
          bf16x8 bl = gfl[(nfg * 4 + ks) * 64 + lane];
          #pragma unroll
          for (int j = 0; j < 3; ++j) {
            int a = ha * 3 + j;
            acc[a][jn] = MFMA16(ah[j], bh, acc[a][jn], 0, 0, 0);
            acc[a][jn] = MFMA16(al[j], bh, acc[a][jn], 0, 0, 0);
            acc[a][jn] = MFMA16(ah[j], bl, acc[a][jn], 0, 0, 0);
          }
        }
      }
    }
    #pragma unroll
    for (int jn = 0; jn < 2; ++jn) {
      #pragma unroll
      for (int rg = 0; rg < 4; ++rg) {
        float mm = acc[0][jn][rg];
        #pragma unroll
        for (int a = 1; a < 6; ++a) mm = fminf(mm, acc[a][jn][rg]);
        mreg[grp * 2 + jn][rg] = mm;
      }
    }
  }
  __syncthreads();
  {
    float* dst = (wv >= 2) ? vmin_s : umin_s;
    int cbase = (wv & 1) * 128;
    #pragma unroll
    for (int j = 0; j < 8; ++j) {
      int colg = cbase + j * 16 + r15;
      #pragma unroll
      for (int rg = 0; rg < 4; ++rg)
        dst[(q * 4 + rg) * OV + colg] = mreg[j][rg];
    }
  }
  __syncthreads();
  #pragma unroll
  for (int j = 0; j < 16; ++j) {
    int i = j * 256 + t;
    int r = i >> 8, g = i & 255;
    out[(size_t)(b0 + r) * 256 + g] =
        fmaxf(umin_s[r * OV + g] + vmin_s[r * OV + g] + gfcn_b[g], 0.f);
  }
}

extern "C" void kernel_launch(void* const* d_in, const int* in_sizes, int n_in,
                              void* d_out, int out_size, void* d_ws, size_t ws_size,
                              hipStream_t stream) {
  const int* a_ids = (const int*)d_in[0];
  const int* b_ids = (const int*)d_in[1];
  const int* c_ids = (const int*)d_in[2];
  const int* event_ids = (const int*)d_in[3];
  const float* node_features = (const float*)d_in[4];
  const float* cond_rel = (const float*)d_in[5];
  const float* text = (const float*)d_in[6];
  const float* entity_emb = (const float*)d_in[7];
  const float* role_emb = (const float*)d_in[8];
  const float* node_W = (const float*)d_in[9];
  const float* node_b = (const float*)d_in[10];
  const float* conv_W = (const float*)d_in[11];
  const float* conv_b = (const float*)d_in[12];
  const float* bn_gamma = (const float*)d_in[13];
  const float* bn_beta = (const float*)d_in[14];
  const float* bn_mean = (const float*)d_in[15];
  const float* bn_var = (const float*)d_in[16];
  const float* gfcn_W = (const float*)d_in[17];
  const float* gfcn_b = (const float*)d_in[18];
  float* out = (float*)d_out;

  short* wsS = (short*)d_ws;
  float* bias_af = (float*)((char*)d_ws + OFF_BIAS_BYTES);
  const int B = in_sizes[0];   // 32768
  const int NT = B / 16;       // 2048

  setup_kernel<<<452, 256, 0, stream>>>(node_W, conv_W, gfcn_W, role_emb,
                                        conv_b, bn_gamma, bn_beta, bn_mean,
                                        bn_var, wsS, bias_af);
  if (ws_size >= WS_NEED && NT <= NT_MAX) {
    short* vfh = (short*)((char*)d_ws + OFF_VF_BYTES);
    short* vfl = vfh + VF_SH;
    ent_kernel<<<NT, 256, 0, stream>>>(a_ids, b_ids, c_ids, event_ids,
                                       node_features, entity_emb, node_b,
                                       wsS, vfh, vfl);
    head_kernel<<<NT, 256, 0, stream>>>(cond_rel, text, gfcn_b, wsS, bias_af,
                                        vfh, vfl, out);
  } else {
    fused_fallback<<<NT, 256, 0, stream>>>(
        a_ids, b_ids, c_ids, event_ids, node_features, cond_rel, text,
        entity_emb, node_b, gfcn_b, wsS, bias_af, out);
  }
}

// Round 8
// 387.178 us; speedup vs baseline: 1.0895x; 1.0895x over previous
//
#include <hip/hip_runtime.h>
#include <hip/hip_bf16.h>

typedef short bf16x8 __attribute__((ext_vector_type(8)));
typedef float f32x4 __attribute__((ext_vector_type(4)));
#define MFMA16 __builtin_amdgcn_mfma_f32_16x16x32_bf16

// ---- split-bf16 helpers -----------------------------------------------------
__device__ __forceinline__ unsigned short rne_bf16(float f) {
  unsigned u = __builtin_bit_cast(unsigned, f);
  return (unsigned short)((u + 0x7fffu + ((u >> 16) & 1u)) >> 16);
}
__device__ __forceinline__ float bf16f(unsigned short h) {
  unsigned u = ((unsigned)h) << 16;
  return __builtin_bit_cast(float, u);
}
__device__ __forceinline__ void split2(float f, short& h, short& l) {
  unsigned short hh = rne_bf16(f);
  h = (short)hh;
  l = (short)rne_bf16(f - bf16f(hh));
}

// ---- ws layout --------------------------------------------------------------
constexpr int NW_SH = 32768;   // node_W  256x128
constexpr int WC_SH = 16384;   // WcEt    128x128
constexpr int GF_SH = 65536;   // gfcn    128x512
constexpr int OFF_NWH = 0;
constexpr int OFF_NWL = NW_SH;
constexpr int OFF_WCH = 2 * NW_SH;
constexpr int OFF_WCL = 2 * NW_SH + WC_SH;
constexpr int OFF_GFH = 2 * NW_SH + 2 * WC_SH;
constexpr int OFF_GFL = 2 * NW_SH + 2 * WC_SH + GF_SH;
constexpr size_t OFF_BIAS_BYTES = (size_t)(2 * NW_SH + 2 * WC_SH + 2 * GF_SH) * 2; // 458752
constexpr size_t OFF_VF_BYTES = OFF_BIAS_BYTES + 6 * 128 * 4;                      // 461824
constexpr int NT_MAX = 2048;                    // B/16
constexpr int VF_SH = NT_MAX * 4 * 4 * 64 * 8;  // 16777216 shorts per plane
constexpr size_t WS_NEED = OFF_VF_BYTES + (size_t)2 * (size_t)VF_SH * 2;           // ~67.6 MB

// ---- setup: pack weights into MFMA fragment layout (hi/lo bf16 planes) ------
__global__ __launch_bounds__(256) void setup_kernel(
    const float* __restrict__ node_W, const float* __restrict__ conv_W,
    const float* __restrict__ gfcn_W, const float* __restrict__ role_emb,
    const float* __restrict__ conv_b, const float* __restrict__ bn_gamma,
    const float* __restrict__ bn_beta, const float* __restrict__ bn_mean,
    const float* __restrict__ bn_var, short* __restrict__ wsS,
    float* __restrict__ bias_af) {
  int idx = blockIdx.x * 256 + threadIdx.x;
  int stride = gridDim.x * 256;
  for (int i = idx; i < 115456; i += stride) {
    if (i < 114688) {
      int j = i & 7, lane = (i >> 3) & 63;
      int kq = ((lane >> 4) & 3) * 8 + j, n16 = lane & 15;
      float val;
      short *ph, *pl;
      int loc;
      if (i < NW_SH) {
        loc = i;
        int f = i >> 9, kf = f & 7, nfr = f >> 3;
        int k = kf * 32 + kq, n = nfr * 16 + n16;
        val = node_W[k * 128 + n];
        ph = wsS + OFF_NWH; pl = wsS + OFF_NWL;
      } else if (i < NW_SH + WC_SH) {
        loc = i - NW_SH;
        int f = loc >> 9, kf = f & 3, nfr = f >> 2;
        int k = kf * 32 + kq, n = nfr * 16 + n16;
        float s = bn_gamma[n] * rsqrtf(bn_var[n] + 1e-5f);
        val = s * conv_W[n * 256 + 128 + k];     // WcEt[e=k][f=n]
        ph = wsS + OFF_WCH; pl = wsS + OFF_WCL;
      } else {
        loc = i - NW_SH - WC_SH;
        int f = loc >> 9, kf = f & 3, nfr = f >> 2;   // nfr 0..31
        int k = kf * 32 + kq, n = nfr * 16 + n16;     // n 0..511
        val = (n < 256) ? gfcn_W[k * 256 + n]
                        : gfcn_W[(128 + k) * 256 + (n - 256)];
        ph = wsS + OFF_GFH; pl = wsS + OFF_GFL;
      }
      short h, l;
      split2(val, h, l);
      ph[loc] = h; pl[loc] = l;
    } else {
      int loc = i - 114688;
      int a = loc >> 7, fc = loc & 127;
      int role = (a == 5) ? 6 : a;   // ROLES = {0,1,2,3,4,6}
      float s = bn_gamma[fc] * rsqrtf(bn_var[fc] + 1e-5f);
      float dot = 0.f;
      for (int e = 0; e < 128; ++e)
        dot = fmaf(role_emb[role * 128 + e], conv_W[fc * 256 + e], dot);
      bias_af[loc] = s * (dot + conv_b[fc] - bn_mean[fc]) + bn_beta[fc];
    }
  }
}

// ---- kernel A: vals[a] = entity + relu(nf@node_W + node_b) -> ws A-frags ----
__global__ __launch_bounds__(256) void ent_kernel(
    const int* __restrict__ a_ids, const int* __restrict__ b_ids,
    const int* __restrict__ c_ids, const int* __restrict__ event_ids,
    const float* __restrict__ nf, const float* __restrict__ ent,
    const float* __restrict__ node_b, const short* __restrict__ wsS,
    short* __restrict__ vfh, short* __restrict__ vfl) {
  __shared__ __align__(16) short lhs[64 * 128];
  __shared__ __align__(16) short lls[64 * 128];
  const int t = threadIdx.x;
  const int wv = t >> 6, lane = t & 63;
  const int r15 = lane & 15, q = lane >> 4;
  const int tile = blockIdx.x;
  const int b0 = tile * 16;

  const bf16x8* nwh = (const bf16x8*)(wsS + OFF_NWH);
  const bf16x8* nwl = (const bf16x8*)(wsS + OFF_NWL);

  const int* pw = (wv == 0) ? a_ids : (wv == 1) ? event_ids
                : (wv == 2) ? b_ids : c_ids;
  int my_id = pw[b0 + r15];
  int eid[4];
  #pragma unroll
  for (int rg = 0; rg < 4; ++rg) eid[rg] = pw[b0 + q * 4 + rg];
  const float* arow = nf + (size_t)my_id * 256 + q * 8;

  float4 avA[8];
  #pragma unroll
  for (int ks = 0; ks < 4; ++ks) {
    avA[2 * ks]     = *(const float4*)(arow + ks * 32);
    avA[2 * ks + 1] = *(const float4*)(arow + ks * 32 + 4);
  }

  f32x4 acc[8];
  #pragma unroll
  for (int n8 = 0; n8 < 8; ++n8) acc[n8] = (f32x4){0.f, 0.f, 0.f, 0.f};
  float4 avB[8];
  #pragma unroll
  for (int ks = 0; ks < 4; ++ks) {
    avB[2 * ks]     = *(const float4*)(arow + (4 + ks) * 32);
    avB[2 * ks + 1] = *(const float4*)(arow + (4 + ks) * 32 + 4);
  }
  #pragma unroll
  for (int ks = 0; ks < 8; ++ks) {
    bf16x8 ah, al;
    {
      float4 v0 = (ks < 4) ? avA[2 * ks] : avB[2 * (ks - 4)];
      float4 v1 = (ks < 4) ? avA[2 * ks + 1] : avB[2 * (ks - 4) + 1];
      #pragma unroll
      for (int j = 0; j < 4; ++j) {
        short h, l;
        split2(v0[j], h, l);
        ah[j] = h; al[j] = l;
        split2(v1[j], h, l);
        ah[4 + j] = h; al[4 + j] = l;
      }
    }
    #pragma unroll
    for (int n8 = 0; n8 < 8; ++n8) {
      bf16x8 bh = nwh[(n8 * 8 + ks) * 64 + lane];
      bf16x8 bl = nwl[(n8 * 8 + ks) * 64 + lane];
      acc[n8] = MFMA16(ah, bh, acc[n8], 0, 0, 0);
      acc[n8] = MFMA16(al, bh, acc[n8], 0, 0, 0);
      acc[n8] = MFMA16(ah, bl, acc[n8], 0, 0, 0);
    }
  }
  float ev[32];
  #pragma unroll
  for (int n8 = 0; n8 < 8; ++n8)
    #pragma unroll
    for (int rg = 0; rg < 4; ++rg)
      ev[n8 * 4 + rg] = ent[(size_t)eid[rg] * 128 + n8 * 16 + r15];
  #pragma unroll
  for (int n8 = 0; n8 < 8; ++n8) {
    int col = n8 * 16 + r15;
    float nb = node_b[col];
    #pragma unroll
    for (int rg = 0; rg < 4; ++rg) {
      float v = ev[n8 * 4 + rg] + fmaxf(acc[n8][rg] + nb, 0.f);
      short h, l; split2(v, h, l);
      int row = wv * 16 + q * 4 + rg;
      int si = row * 128 + (col ^ ((row & 7) << 3));
      lhs[si] = h; lls[si] = l;
    }
  }
  __syncthreads();
  #pragma unroll
  for (int ks = 0; ks < 4; ++ks) {
    int row = wv * 16 + r15;
    int k0 = ks * 32 + q * 8;
    int si = row * 128 + (k0 ^ ((row & 7) << 3));
    ((bf16x8*)vfh)[((tile * 4 + wv) * 4 + ks) * 64 + lane] = *(const bf16x8*)&lhs[si];
    ((bf16x8*)vfl)[((tile * 4 + wv) * 4 + ks) * 64 + lane] = *(const bf16x8*)&lls[si];
  }
}

// ---- head body: stages C+D, 512 threads / 8 waves ---------------------------
__device__ __forceinline__ void head_body(
    int tile, const float* __restrict__ cond, const float* __restrict__ text,
    const float* __restrict__ gfcn_b, const short* __restrict__ wsS,
    const float* __restrict__ bias_af, const short* __restrict__ vfh,
    const short* __restrict__ vfl, float* __restrict__ out,
    unsigned char* smem) {
  short* lds_hi = (short*)smem;                 // 96x128 bf16 hi plane
  short* lds_lo = (short*)(smem + 24576);       // lo plane
  float* umin_s = (float*)smem;                 // overlay after planes dead
  constexpr int OV = 260;

  const int t = threadIdx.x;
  const int wv = t >> 6, lane = t & 63;
  const int r15 = lane & 15, q = lane >> 4;
  const int b0 = tile * 16;

  const bf16x8* wch = (const bf16x8*)(wsS + OFF_WCH);
  const bf16x8* wcl = (const bf16x8*)(wsS + OFF_WCL);
  const bf16x8* gfh = (const bf16x8*)(wsS + OFF_GFH);
  const bf16x8* gfl = (const bf16x8*)(wsS + OFF_GFL);
  const bf16x8* vfh8 = (const bf16x8*)vfh;
  const bf16x8* vfl8 = (const bf16x8*)vfl;

  // ---- Phase 0: stage cond/text rows (a=4,5) into plane rows 64..95 ---------
  #pragma unroll
  for (int j = 0; j < 8; ++j) {
    int i = j * 512 + t;
    int arr = i >> 11, rem = i & 2047, r = rem >> 7, e = rem & 127;
    const float* src = arr ? text : cond;
    float v = src[(size_t)(b0 + r) * 128 + e];
    short h, l;
    split2(v, h, l);
    int row = (4 + arr) * 16 + r;
    int si = row * 128 + (e ^ ((row & 7) << 3));
    lds_hi[si] = h; lds_lo[si] = l;
  }
  __syncthreads();

  // ---- Stage C: x = relu(vals @ WcEt + bias_af); wave owns n-frag wv --------
  {
    f32x4 xacc[6];
    #pragma unroll
    for (int a = 0; a < 6; ++a) xacc[a] = (f32x4){0.f, 0.f, 0.f, 0.f};
    #pragma unroll
    for (int ks = 0; ks < 4; ++ks) {
      int k0 = ks * 32 + q * 8;
      bf16x8 bh = wch[(wv * 4 + ks) * 64 + lane];
      bf16x8 bl = wcl[(wv * 4 + ks) * 64 + lane];
      #pragma unroll
      for (int ha = 0; ha < 2; ++ha) {
        bf16x8 ah[3], al[3];
        #pragma unroll
        for (int j = 0; j < 3; ++j) {
          int a = ha * 3 + j;
          if (a < 4) {
            ah[j] = vfh8[((tile * 4 + a) * 4 + ks) * 64 + lane];
            al[j] = vfl8[((tile * 4 + a) * 4 + ks) * 64 + lane];
          } else {
            int row = a * 16 + r15;
            int si = row * 128 + (k0 ^ ((row & 7) << 3));
            ah[j] = *(const bf16x8*)&lds_hi[si];
            al[j] = *(const bf16x8*)&lds_lo[si];
          }
        }
        #pragma unroll
        for (int j = 0; j < 3; ++j) {
          int a = ha * 3 + j;
          xacc[a] = MFMA16(ah[j], bh, xacc[a], 0, 0, 0);
          xacc[a] = MFMA16(al[j], bh, xacc[a], 0, 0, 0);
          xacc[a] = MFMA16(ah[j], bl, xacc[a], 0, 0, 0);
        }
      }
    }
    __syncthreads();   // all cond/text plane reads done before x overwrites
    #pragma unroll
    for (int a = 0; a < 6; ++a) {
      int col = wv * 16 + r15;
      float bv = bias_af[a * 128 + col];
      #pragma unroll
      for (int rg = 0; rg < 4; ++rg) {
        float v = fmaxf(xacc[a][rg] + bv, 0.f);
        short h, l; split2(v, h, l);
        int row = a * 16 + q * 4 + rg;
        int si = row * 128 + (col ^ ((row & 7) << 3));
        lds_hi[si] = h; lds_lo[si] = l;
      }
    }
  }
  __syncthreads();

  // ---- Stage D: u/v = x @ gfcn, min over a; 2 passes x 2 jn -----------------
  f32x4 mreg[4];
  #pragma unroll
  for (int gp = 0; gp < 2; ++gp) {
    f32x4 acc[6][2];
    #pragma unroll
    for (int a = 0; a < 6; ++a) {
      acc[a][0] = (f32x4){0.f, 0.f, 0.f, 0.f};
      acc[a][1] = (f32x4){0.f, 0.f, 0.f, 0.f};
    }
    #pragma unroll
    for (int ks = 0; ks < 4; ++ks) {
      int k0 = ks * 32 + q * 8;
      #pragma unroll
      for (int ha = 0; ha < 2; ++ha) {
        bf16x8 ah[3], al[3];
        #pragma unroll
        for (int j = 0; j < 3; ++j) {
          int row = (ha * 3 + j) * 16 + r15;
          int si = row * 128 + (k0 ^ ((row & 7) << 3));
          ah[j] = *(const bf16x8*)&lds_hi[si];
          al[j] = *(const bf16x8*)&lds_lo[si];
        }
        #pragma unroll
        for (int jn = 0; jn < 2; ++jn) {
          int nfg = wv * 4 + gp * 2 + jn;
          bf16x8 bh = gfh[(nfg * 4 + ks) * 64 + lane];
          bf16x8 bl = gfl[(nfg * 4 + ks) * 64 + lane];
          #pragma unroll
          for (int j = 0; j < 3; ++j) {
            int a = ha * 3 + j;
            acc[a][jn] = MFMA16(ah[j], bh, acc[a][jn], 0, 0, 0);
            acc[a][jn] = MFMA16(al[j], bh, acc[a][jn], 0, 0, 0);
            acc[a][jn] = MFMA16(ah[j], bl, acc[a][jn], 0, 0, 0);
          }
        }
      }
    }
    #pragma unroll
    for (int jn = 0; jn < 2; ++jn) {
      #pragma unroll
      for (int rg = 0; rg < 4; ++rg) {
        float mm = acc[0][jn][rg];
        #pragma unroll
        for (int a = 1; a < 6; ++a) mm = fminf(mm, acc[a][jn][rg]);
        mreg[gp * 2 + jn][rg] = mm;
      }
    }
  }
  __syncthreads();   // all x reads done; planes now dead

  if (wv < 4) {      // u waves: write umin to overlay
    #pragma unroll
    for (int j = 0; j < 4; ++j) {
      int colg = wv * 64 + j * 16 + r15;
      #pragma unroll
      for (int rg = 0; rg < 4; ++rg)
        umin_s[(q * 4 + rg) * OV + colg] = mreg[j][rg];
    }
  }
  __syncthreads();
  if (wv >= 4) {     // v waves: combine in-reg vmin with LDS umin, write out
    #pragma unroll
    for (int j = 0; j < 4; ++j) {
      int g = (wv - 4) * 64 + j * 16 + r15;
      float gbv = gfcn_b[g];
      #pragma unroll
      for (int rg = 0; rg < 4; ++rg) {
        int r = q * 4 + rg;
        out[(size_t)(b0 + r) * 256 + g] =
            fmaxf(umin_s[r * OV + g] + mreg[j][rg] + gbv, 0.f);
      }
    }
  }
}

__global__ __launch_bounds__(512, 4) void head_kernel_f(
    int tile_off, const float* __restrict__ cond, const float* __restrict__ text,
    const float* __restrict__ gfcn_b, const short* __restrict__ wsS,
    const float* __restrict__ bias_af, const short* __restrict__ vfh,
    const short* __restrict__ vfl, float* __restrict__ out) {
  __shared__ __align__(16) unsigned char smem[49152];
  head_body(blockIdx.x + tile_off, cond, text, gfcn_b, wsS, bias_af, vfh, vfl,
            out, smem);
}

__global__ __launch_bounds__(512, 2) void head_kernel_n(
    int tile_off, const float* __restrict__ cond, const float* __restrict__ text,
    const float* __restrict__ gfcn_b, const short* __restrict__ wsS,
    const float* __restrict__ bias_af, const short* __restrict__ vfh,
    const short* __restrict__ vfl, float* __restrict__ out) {
  __shared__ __align__(16) unsigned char smem[49152];
  head_body(blockIdx.x + tile_off, cond, text, gfcn_b, wsS, bias_af, vfh, vfl,
            out, smem);
}

// ---- fallback: fused (R5 structure, no min-wave bound) ----------------------
__global__ __launch_bounds__(256) void fused_fallback(
    const int* __restrict__ a_ids, const int* __restrict__ b_ids,
    const int* __restrict__ c_ids, const int* __restrict__ event_ids,
    const float* __restrict__ nf, const float* __restrict__ cond,
    const float* __restrict__ text, const float* __restrict__ ent,
    const float* __restrict__ node_b, const float* __restrict__ gfcn_b,
    const short* __restrict__ wsS, const float* __restrict__ bias_af,
    float* __restrict__ out) {
  __shared__ __align__(16) unsigned char smem[49152];
  short* lds_hi = (short*)smem;
  short* lds_lo = (short*)(smem + 24576);
  float* umin_s = (float*)smem;
  float* vmin_s = (float*)(smem + 16640);
  constexpr int OV = 260;

  const int t = threadIdx.x;
  const int wv = t >> 6, lane = t & 63;
  const int r15 = lane & 15, q = lane >> 4;
  const int b0 = blockIdx.x * 16;

  const bf16x8* nwh = (const bf16x8*)(wsS + OFF_NWH);
  const bf16x8* nwl = (const bf16x8*)(wsS + OFF_NWL);
  const bf16x8* wch = (const bf16x8*)(wsS + OFF_WCH);
  const bf16x8* wcl = (const bf16x8*)(wsS + OFF_WCL);
  const bf16x8* gfh = (const bf16x8*)(wsS + OFF_GFH);
  const bf16x8* gfl = (const bf16x8*)(wsS + OFF_GFL);

  const int* pw = (wv == 0) ? a_ids : (wv == 1) ? event_ids
                : (wv == 2) ? b_ids : c_ids;
  int my_id = pw[b0 + r15];
  int eid[4];
  #pragma unroll
  for (int rg = 0; rg < 4; ++rg) eid[rg] = pw[b0 + q * 4 + rg];
  const float* arow = nf + (size_t)my_id * 256 + q * 8;

  float4 avA[8];
  #pragma unroll
  for (int ks = 0; ks < 4; ++ks) {
    avA[2 * ks]     = *(const float4*)(arow + ks * 32);
    avA[2 * ks + 1] = *(const float4*)(arow + ks * 32 + 4);
  }
  #pragma unroll
  for (int j = 0; j < 16; ++j) {
    int i = j * 256 + t;
    int arr = i >> 11, rem = i & 2047, r = rem >> 7, e = rem & 127;
    const float* src = arr ? text : cond;
    float v = src[(size_t)(b0 + r) * 128 + e];
    short h, l;
    split2(v, h, l);
    int row = (4 + arr) * 16 + r;
    int si = row * 128 + (e ^ ((row & 7) << 3));
    lds_hi[si] = h; lds_lo[si] = l;
  }
  {
    f32x4 acc[8];
    #pragma unroll
    for (int n8 = 0; n8 < 8; ++n8) acc[n8] = (f32x4){0.f, 0.f, 0.f, 0.f};
    float4 avB[8];
    #pragma unroll
    for (int ks = 0; ks < 4; ++ks) {
      avB[2 * ks]     = *(const float4*)(arow + (4 + ks) * 32);
      avB[2 * ks + 1] = *(const float4*)(arow + (4 + ks) * 32 + 4);
    }
    #pragma unroll
    for (int ks = 0; ks < 8; ++ks) {
      bf16x8 ah, al;
      {
        float4 v0 = (ks < 4) ? avA[2 * ks] : avB[2 * (ks - 4)];
        float4 v1 = (ks < 4) ? avA[2 * ks + 1] : avB[2 * (ks - 4) + 1];
        #pragma unroll
        for (int j = 0; j < 4; ++j) {
          short h, l;
          split2(v0[j], h, l);
          ah[j] = h; al[j] = l;
          split2(v1[j], h, l);
          ah[4 + j] = h; al[4 + j] = l;
        }
      }
      #pragma unroll
      for (int n8 = 0; n8 < 8; ++n8) {
        bf16x8 bh = nwh[(n8 * 8 + ks) * 64 + lane];
        bf16x8 bl = nwl[(n8 * 8 + ks) * 64 + lane];
        acc[n8] = MFMA16(ah, bh, acc[n8], 0, 0, 0);
        acc[n8] = MFMA16(al, bh, acc[n8], 0, 0, 0);
        acc[n8] = MFMA16(ah, bl, acc[n8], 0, 0, 0);
      }
    }
    float ev[32];
    #pragma unroll
    for (int n8 = 0; n8 < 8; ++n8)
      #pragma unroll
      for (int rg = 0; rg < 4; ++rg)
        ev[n8 * 4 + rg] = ent[(size_t)eid[rg] * 128 + n8 * 16 + r15];
    #pragma unroll
    for (int n8 = 0; n8 < 8; ++n8) {
      int col = n8 * 16 + r15;
      float nb = node_b[col];
      #pragma unroll
      for (int rg = 0; rg < 4; ++rg) {
        float v = ev[n8 * 4 + rg] + fmaxf(acc[n8][rg] + nb, 0.f);
        short h, l; split2(v, h, l);
        int row = wv * 16 + q * 4 + rg;
        int si = row * 128 + (col ^ ((row & 7) << 3));
        lds_hi[si] = h; lds_lo[si] = l;
      }
    }
  }
  __syncthreads();
  {
    f32x4 xacc[6][2];
    #pragma unroll
    for (int a = 0; a < 6; ++a) {
      xacc[a][0] = (f32x4){0.f, 0.f, 0.f, 0.f};
      xacc[a][1] = (f32x4){0.f, 0.f, 0.f, 0.f};
    }
    #pragma unroll
    for (int ks = 0; ks < 4; ++ks) {
      int k0 = ks * 32 + q * 8;
      #pragma unroll
      for (int ha = 0; ha < 2; ++ha) {
        bf16x8 ah[3], al[3];
        #pragma unroll
        for (int j = 0; j < 3; ++j) {
          int row = (ha * 3 + j) * 16 + r15;
          int si = row * 128 + (k0 ^ ((row & 7) << 3));
          ah[j] = *(const bf16x8*)&lds_hi[si];
          al[j] = *(const bf16x8*)&lds_lo[si];
        }
        #pragma unroll
        for (int jn = 0; jn < 2; ++jn) {
          bf16x8 bh = wch[((wv * 2 + jn) * 4 + ks) * 64 + lane];
          bf16x8 bl = wcl[((wv * 2 + jn) * 4 + ks) * 64 + lane];
          #pragma unroll
          for (int j = 0; j < 3; ++j) {
            int a = ha * 3 + j;
            xacc[a][jn] = MFMA16(ah[j], bh, xacc[a][jn], 0, 0, 0);
            xacc[a][jn] = MFMA16(al[j], bh, xacc[a][jn], 0, 0, 0);
            xacc[a][jn] = MFMA16(ah[j], bl, xacc[a][jn], 0, 0, 0);
          }
        }
      }
    }
    __syncthreads();
    #pragma unroll
    for (int a = 0; a < 6; ++a) {
      #pragma unroll
      for (int jn = 0; jn < 2; ++jn) {
        int col = (wv * 2 + jn) * 16 + r15;
        float bv = bias_af[a * 128 + col];
        #pragma unroll
        for (int rg = 0; rg < 4; ++rg) {
          float v = fmaxf(xacc[a][jn][rg] + bv, 0.f);
          short h, l; split2(v, h, l);
          int row = a * 16 + q * 4 + rg;
          int si = row * 128 + (col ^ ((row & 7) << 3));
          lds_hi[si] = h; lds_lo[si] = l;
        }
      }
    }
  }
  __syncthreads();
  f32x4 mreg[8];
  #pragma unroll
  for (int grp = 0; grp < 4; ++grp) {
    f32x4 acc[6][2];
    #pragma unroll
    for (int a = 0; a < 6; ++a) {
      acc[a][0] = (f32x4){0.f, 0.f, 0.f, 0.f};
      acc[a][1] = (f32x4){0.f, 0.f, 0.f, 0.f};
    }
    #pragma unroll
    for (int ks = 0; ks < 4; ++ks) {
      int k0 = ks * 32 + q * 8;
      #pragma unroll
      for (int ha = 0; ha < 2; ++ha) {
        bf16x8 ah[3], al[3];
        #pragma unroll
        for (int j = 0; j < 3; ++j) {
          int row = (ha * 3 + j) * 16 + r15;
          int si = row * 128 + (k0 ^ ((row & 7) << 3));
          ah[j] = *(const bf16x8*)&lds_hi[si];
          al[j] = *(const bf16x8*)&lds_lo[si];
        }
        #pragma unroll
        for (int jn = 0; jn < 2; ++jn) {
          int nfg = wv * 8 + grp * 2 + jn;
          bf16x8 bh = gfh[(nfg * 4 + ks) * 64 + lane];
          bf16x8 bl = gfl[(nfg * 4 + ks) * 64 + lane];
          #pragma unroll
          for (int j = 0; j < 3; ++j) {
            int a = ha * 3 + j;
            acc[a][jn] = MFMA16(ah[j], bh, acc[a][jn], 0, 0, 0);
            acc[a][jn] = MFMA16(al[j], bh, acc[a][jn], 0, 0, 0);
            acc[a][jn] = MFMA16(ah[j], bl, acc[a][jn], 0, 0, 0);
          }
        }
      }
    }
    #pragma unroll
    for (int jn = 0; jn < 2; ++jn) {
      #pragma unroll
      for (int rg = 0; rg < 4; ++rg) {
        float mm = acc[0][jn][rg];
        #pragma unroll
        for (int a = 1; a < 6; ++a) mm = fminf(mm, acc[a][jn][rg]);
        mreg[grp * 2 + jn][rg] = mm;
      }
    }
  }
  __syncthreads();
  {
    float* dst = (wv >= 2) ? vmin_s : umin_s;
    int cbase = (wv & 1) * 128;
    #pragma unroll
    for (int j = 0; j < 8; ++j) {
      int colg = cbase + j * 16 + r15;
      #pragma unroll
      for (int rg = 0; rg < 4; ++rg)
        dst[(q * 4 + rg) * OV + colg] = mreg[j][rg];
    }
  }
  __syncthreads();
  #pragma unroll
  for (int j = 0; j < 16; ++j) {
    int i = j * 256 + t;
    int r = i >> 8, g = i & 255;
    out[(size_t)(b0 + r) * 256 + g] =
        fmaxf(umin_s[r * OV + g] + vmin_s[r * OV + g] + gfcn_b[g], 0.f);
  }
}

extern "C" void kernel_launch(void* const* d_in, const int* in_sizes, int n_in,
                              void* d_out, int out_size, void* d_ws, size_t ws_size,
                              hipStream_t stream) {
  const int* a_ids = (const int*)d_in[0];
  const int* b_ids = (const int*)d_in[1];
  const int* c_ids = (const int*)d_in[2];
  const int* event_ids = (const int*)d_in[3];
  const float* node_features = (const float*)d_in[4];
  const float* cond_rel = (const float*)d_in[5];
  const float* text = (const float*)d_in[6];
  const float* entity_emb = (const float*)d_in[7];
  const float* role_emb = (const float*)d_in[8];
  const float* node_W = (const float*)d_in[9];
  const float* node_b = (const float*)d_in[10];
  const float* conv_W = (const float*)d_in[11];
  const float* conv_b = (const float*)d_in[12];
  const float* bn_gamma = (const float*)d_in[13];
  const float* bn_beta = (const float*)d_in[14];
  const float* bn_mean = (const float*)d_in[15];
  const float* bn_var = (const float*)d_in[16];
  const float* gfcn_W = (const float*)d_in[17];
  const float* gfcn_b = (const float*)d_in[18];
  float* out = (float*)d_out;

  short* wsS = (short*)d_ws;
  float* bias_af = (float*)((char*)d_ws + OFF_BIAS_BYTES);
  const int B = in_sizes[0];   // 32768
  const int NT = B / 16;       // 2048

  setup_kernel<<<452, 256, 0, stream>>>(node_W, conv_W, gfcn_W, role_emb,
                                        conv_b, bn_gamma, bn_beta, bn_mean,
                                        bn_var, wsS, bias_af);
  if (ws_size >= WS_NEED && NT <= NT_MAX && (NT % 2) == 0) {
    short* vfh = (short*)((char*)d_ws + OFF_VF_BYTES);
    short* vfl = vfh + VF_SH;
    ent_kernel<<<NT, 256, 0, stream>>>(a_ids, b_ids, c_ids, event_ids,
                                       node_features, entity_emb, node_b,
                                       wsS, vfh, vfl);
    // A/B within round: forced (512,4) on first half, safe (512,2) on second
    head_kernel_f<<<NT / 2, 512, 0, stream>>>(0, cond_rel, text, gfcn_b, wsS,
                                              bias_af, vfh, vfl, out);
    head_kernel_n<<<NT / 2, 512, 0, stream>>>(NT / 2, cond_rel, text, gfcn_b,
                                              wsS, bias_af, vfh, vfl, out);
  } else {
    fused_fallback<<<NT, 256, 0, stream>>>(
        a_ids, b_ids, c_ids, event_ids, node_features, cond_rel, text,
        entity_emb, node_b, gfcn_b, wsS, bias_af, out);
  }
}

// Round 9
// 213.400 us; speedup vs baseline: 1.9767x; 1.8143x over previous
//
#include <hip/hip_runtime.h>
#include <hip/hip_bf16.h>

typedef short bf16x8 __attribute__((ext_vector_type(8)));
typedef float f32x4 __attribute__((ext_vector_type(4)));
#define MFMA16 __builtin_amdgcn_mfma_f32_16x16x32_bf16

// ---- split-bf16 helpers -----------------------------------------------------
__device__ __forceinline__ unsigned short rne_bf16(float f) {
  unsigned u = __builtin_bit_cast(unsigned, f);
  return (unsigned short)((u + 0x7fffu + ((u >> 16) & 1u)) >> 16);
}
__device__ __forceinline__ float bf16f(unsigned short h) {
  unsigned u = ((unsigned)h) << 16;
  return __builtin_bit_cast(float, u);
}
__device__ __forceinline__ void split2(float f, short& h, short& l) {
  unsigned short hh = rne_bf16(f);
  h = (short)hh;
  l = (short)rne_bf16(f - bf16f(hh));
}

// ---- ws layout --------------------------------------------------------------
constexpr int NW_SH = 32768;   // node_W  256x128
constexpr int WC_SH = 16384;   // WcEt    128x128
constexpr int GF_SH = 65536;   // gfcn    128x512
constexpr int OFF_NWH = 0;
constexpr int OFF_NWL = NW_SH;
constexpr int OFF_WCH = 2 * NW_SH;
constexpr int OFF_WCL = 2 * NW_SH + WC_SH;
constexpr int OFF_GFH = 2 * NW_SH + 2 * WC_SH;
constexpr int OFF_GFL = 2 * NW_SH + 2 * WC_SH + GF_SH;
constexpr size_t OFF_BIAS_BYTES = (size_t)(2 * NW_SH + 2 * WC_SH + 2 * GF_SH) * 2; // 458752
constexpr size_t OFF_VF_BYTES = OFF_BIAS_BYTES + 6 * 128 * 4;                      // 461824
constexpr int NT_MAX = 2048;                    // B/16
constexpr int VF_SH = NT_MAX * 4 * 4 * 64 * 8;  // 16777216 shorts per plane
constexpr size_t WS_NEED = OFF_VF_BYTES + (size_t)2 * (size_t)VF_SH * 2;           // ~67.6 MB

// ---- setup: pack weights into MFMA fragment layout (hi/lo bf16 planes) ------
__global__ __launch_bounds__(256) void setup_kernel(
    const float* __restrict__ node_W, const float* __restrict__ conv_W,
    const float* __restrict__ gfcn_W, const float* __restrict__ role_emb,
    const float* __restrict__ conv_b, const float* __restrict__ bn_gamma,
    const float* __restrict__ bn_beta, const float* __restrict__ bn_mean,
    const float* __restrict__ bn_var, short* __restrict__ wsS,
    float* __restrict__ bias_af) {
  int idx = blockIdx.x * 256 + threadIdx.x;
  int stride = gridDim.x * 256;
  for (int i = idx; i < 115456; i += stride) {
    if (i < 114688) {
      int j = i & 7, lane = (i >> 3) & 63;
      int kq = ((lane >> 4) & 3) * 8 + j, n16 = lane & 15;
      float val;
      short *ph, *pl;
      int loc;
      if (i < NW_SH) {
        loc = i;
        int f = i >> 9, kf = f & 7, nfr = f >> 3;
        int k = kf * 32 + kq, n = nfr * 16 + n16;
        val = node_W[k * 128 + n];
        ph = wsS + OFF_NWH; pl = wsS + OFF_NWL;
      } else if (i < NW_SH + WC_SH) {
        loc = i - NW_SH;
        int f = loc >> 9, kf = f & 3, nfr = f >> 2;
        int k = kf * 32 + kq, n = nfr * 16 + n16;
        float s = bn_gamma[n] * rsqrtf(bn_var[n] + 1e-5f);
        val = s * conv_W[n * 256 + 128 + k];     // WcEt[e=k][f=n]
        ph = wsS + OFF_WCH; pl = wsS + OFF_WCL;
      } else {
        loc = i - NW_SH - WC_SH;
        int f = loc >> 9, kf = f & 3, nfr = f >> 2;   // nfr 0..31
        int k = kf * 32 + kq, n = nfr * 16 + n16;     // n 0..511
        val = (n < 256) ? gfcn_W[k * 256 + n]
                        : gfcn_W[(128 + k) * 256 + (n - 256)];
        ph = wsS + OFF_GFH; pl = wsS + OFF_GFL;
      }
      short h, l;
      split2(val, h, l);
      ph[loc] = h; pl[loc] = l;
    } else {
      int loc = i - 114688;
      int a = loc >> 7, fc = loc & 127;
      int role = (a == 5) ? 6 : a;   // ROLES = {0,1,2,3,4,6}
      float s = bn_gamma[fc] * rsqrtf(bn_var[fc] + 1e-5f);
      float dot = 0.f;
      for (int e = 0; e < 128; ++e)
        dot = fmaf(role_emb[role * 128 + e], conv_W[fc * 256 + e], dot);
      bias_af[loc] = s * (dot + conv_b[fc] - bn_mean[fc]) + bn_beta[fc];
    }
  }
}

// ---- kernel A: vals[a] = entity + relu(nf@node_W + node_b) -> ws A-frags ----
__global__ __launch_bounds__(256) void ent_kernel(
    const int* __restrict__ a_ids, const int* __restrict__ b_ids,
    const int* __restrict__ c_ids, const int* __restrict__ event_ids,
    const float* __restrict__ nf, const float* __restrict__ ent,
    const float* __restrict__ node_b, const short* __restrict__ wsS,
    short* __restrict__ vfh, short* __restrict__ vfl) {
  __shared__ __align__(16) short lhs[64 * 128];
  __shared__ __align__(16) short lls[64 * 128];
  const int t = threadIdx.x;
  const int wv = t >> 6, lane = t & 63;
  const int r15 = lane & 15, q = lane >> 4;
  const int tile = blockIdx.x;
  const int b0 = tile * 16;

  const bf16x8* nwh = (const bf16x8*)(wsS + OFF_NWH);
  const bf16x8* nwl = (const bf16x8*)(wsS + OFF_NWL);

  const int* pw = (wv == 0) ? a_ids : (wv == 1) ? event_ids
                : (wv == 2) ? b_ids : c_ids;
  int my_id = pw[b0 + r15];
  int eid[4];
  #pragma unroll
  for (int rg = 0; rg < 4; ++rg) eid[rg] = pw[b0 + q * 4 + rg];
  const float* arow = nf + (size_t)my_id * 256 + q * 8;

  float4 avA[8];
  #pragma unroll
  for (int ks = 0; ks < 4; ++ks) {
    avA[2 * ks]     = *(const float4*)(arow + ks * 32);
    avA[2 * ks + 1] = *(const float4*)(arow + ks * 32 + 4);
  }

  f32x4 acc[8];
  #pragma unroll
  for (int n8 = 0; n8 < 8; ++n8) acc[n8] = (f32x4){0.f, 0.f, 0.f, 0.f};
  float4 avB[8];
  #pragma unroll
  for (int ks = 0; ks < 4; ++ks) {
    avB[2 * ks]     = *(const float4*)(arow + (4 + ks) * 32);
    avB[2 * ks + 1] = *(const float4*)(arow + (4 + ks) * 32 + 4);
  }
  #pragma unroll
  for (int ks = 0; ks < 8; ++ks) {
    bf16x8 ah, al;
    {
      float4 v0 = (ks < 4) ? avA[2 * ks] : avB[2 * (ks - 4)];
      float4 v1 = (ks < 4) ? avA[2 * ks + 1] : avB[2 * (ks - 4) + 1];
      #pragma unroll
      for (int j = 0; j < 4; ++j) {
        short h, l;
        split2(v0[j], h, l);
        ah[j] = h; al[j] = l;
        split2(v1[j], h, l);
        ah[4 + j] = h; al[4 + j] = l;
      }
    }
    #pragma unroll
    for (int n8 = 0; n8 < 8; ++n8) {
      bf16x8 bh = nwh[(n8 * 8 + ks) * 64 + lane];
      bf16x8 bl = nwl[(n8 * 8 + ks) * 64 + lane];
      acc[n8] = MFMA16(ah, bh, acc[n8], 0, 0, 0);
      acc[n8] = MFMA16(al, bh, acc[n8], 0, 0, 0);
      acc[n8] = MFMA16(ah, bl, acc[n8], 0, 0, 0);
    }
  }
  float ev[32];
  #pragma unroll
  for (int n8 = 0; n8 < 8; ++n8)
    #pragma unroll
    for (int rg = 0; rg < 4; ++rg)
      ev[n8 * 4 + rg] = ent[(size_t)eid[rg] * 128 + n8 * 16 + r15];
  #pragma unroll
  for (int n8 = 0; n8 < 8; ++n8) {
    int col = n8 * 16 + r15;
    float nb = node_b[col];
    #pragma unroll
    for (int rg = 0; rg < 4; ++rg) {
      float v = ev[n8 * 4 + rg] + fmaxf(acc[n8][rg] + nb, 0.f);
      short h, l; split2(v, h, l);
      int row = wv * 16 + q * 4 + rg;
      int si = row * 128 + (col ^ ((row & 7) << 3));
      lhs[si] = h; lls[si] = l;
    }
  }
  __syncthreads();
  #pragma unroll
  for (int ks = 0; ks < 4; ++ks) {
    int row = wv * 16 + r15;
    int k0 = ks * 32 + q * 8;
    int si = row * 128 + (k0 ^ ((row & 7) << 3));
    ((bf16x8*)vfh)[((tile * 4 + wv) * 4 + ks) * 64 + lane] = *(const bf16x8*)&lhs[si];
    ((bf16x8*)vfl)[((tile * 4 + wv) * 4 + ks) * 64 + lane] = *(const bf16x8*)&lls[si];
  }
}

// ---- kernel B: stages C+D, 512 threads / 8 waves, merged-jn D ---------------
__global__ __launch_bounds__(512) void head_kernel(
    const float* __restrict__ cond, const float* __restrict__ text,
    const float* __restrict__ gfcn_b, const short* __restrict__ wsS,
    const float* __restrict__ bias_af, const short* __restrict__ vfh,
    const short* __restrict__ vfl, float* __restrict__ out) {
  __shared__ __align__(16) unsigned char smem[49152];
  short* lds_hi = (short*)smem;                 // 96x128 bf16 hi plane
  short* lds_lo = (short*)(smem + 24576);       // lo plane
  float* umin_s = (float*)smem;                 // overlay after planes dead
  constexpr int OV = 260;

  const int t = threadIdx.x;
  const int wv = t >> 6, lane = t & 63;
  const int r15 = lane & 15, q = lane >> 4;
  const int tile = blockIdx.x;
  const int b0 = tile * 16;

  const bf16x8* wch = (const bf16x8*)(wsS + OFF_WCH);
  const bf16x8* wcl = (const bf16x8*)(wsS + OFF_WCL);
  const bf16x8* gfh = (const bf16x8*)(wsS + OFF_GFH);
  const bf16x8* gfl = (const bf16x8*)(wsS + OFF_GFL);
  const bf16x8* vfh8 = (const bf16x8*)vfh;
  const bf16x8* vfl8 = (const bf16x8*)vfl;

  // ---- Phase 0: stage cond/text rows (a=4,5) into plane rows 64..95 ---------
  #pragma unroll
  for (int j = 0; j < 8; ++j) {
    int i = j * 512 + t;
    int arr = i >> 11, rem = i & 2047, r = rem >> 7, e = rem & 127;
    const float* src = arr ? text : cond;
    float v = src[(size_t)(b0 + r) * 128 + e];
    short h, l;
    split2(v, h, l);
    int row = (4 + arr) * 16 + r;
    int si = row * 128 + (e ^ ((row & 7) << 3));
    lds_hi[si] = h; lds_lo[si] = l;
  }
  __syncthreads();

  // ---- Stage C: x = relu(vals @ WcEt + bias_af); wave owns n-frag wv --------
  {
    f32x4 xacc[6];
    #pragma unroll
    for (int a = 0; a < 6; ++a) xacc[a] = (f32x4){0.f, 0.f, 0.f, 0.f};
    #pragma unroll
    for (int ks = 0; ks < 4; ++ks) {
      int k0 = ks * 32 + q * 8;
      bf16x8 bh = wch[(wv * 4 + ks) * 64 + lane];
      bf16x8 bl = wcl[(wv * 4 + ks) * 64 + lane];
      #pragma unroll
      for (int ha = 0; ha < 2; ++ha) {
        bf16x8 ah[3], al[3];
        #pragma unroll
        for (int j = 0; j < 3; ++j) {
          int a = ha * 3 + j;
          if (a < 4) {
            ah[j] = vfh8[((tile * 4 + a) * 4 + ks) * 64 + lane];
            al[j] = vfl8[((tile * 4 + a) * 4 + ks) * 64 + lane];
          } else {
            int row = a * 16 + r15;
            int si = row * 128 + (k0 ^ ((row & 7) << 3));
            ah[j] = *(const bf16x8*)&lds_hi[si];
            al[j] = *(const bf16x8*)&lds_lo[si];
          }
        }
        __builtin_amdgcn_s_setprio(1);
        #pragma unroll
        for (int j = 0; j < 3; ++j) {
          int a = ha * 3 + j;
          xacc[a] = MFMA16(ah[j], bh, xacc[a], 0, 0, 0);
          xacc[a] = MFMA16(al[j], bh, xacc[a], 0, 0, 0);
          xacc[a] = MFMA16(ah[j], bl, xacc[a], 0, 0, 0);
        }
        __builtin_amdgcn_s_setprio(0);
      }
    }
    __syncthreads();   // all cond/text plane reads done before x overwrites
    #pragma unroll
    for (int a = 0; a < 6; ++a) {
      int col = wv * 16 + r15;
      float bv = bias_af[a * 128 + col];
      #pragma unroll
      for (int rg = 0; rg < 4; ++rg) {
        float v = fmaxf(xacc[a][rg] + bv, 0.f);
        short h, l; split2(v, h, l);
        int row = a * 16 + q * 4 + rg;
        int si = row * 128 + (col ^ ((row & 7) << 3));
        lds_hi[si] = h; lds_lo[si] = l;
      }
    }
  }
  __syncthreads();

  // ---- Stage D: u/v = x @ gfcn; acc[6][4] merged, A-frag reused 12x ---------
  f32x4 acc[6][4];
  #pragma unroll
  for (int a = 0; a < 6; ++a)
    #pragma unroll
    for (int jn = 0; jn < 4; ++jn) acc[a][jn] = (f32x4){0.f, 0.f, 0.f, 0.f};
  #pragma unroll
  for (int ks = 0; ks < 4; ++ks) {
    int k0 = ks * 32 + q * 8;
    bf16x8 bh[4], bl[4];
    #pragma unroll
    for (int jn = 0; jn < 4; ++jn) {
      int nfg = wv * 4 + jn;
      bh[jn] = gfh[(nfg * 4 + ks) * 64 + lane];
      bl[jn] = gfl[(nfg * 4 + ks) * 64 + lane];
    }
    #pragma unroll
    for (int ha = 0; ha < 2; ++ha) {
      bf16x8 ah[3], al[3];
      #pragma unroll
      for (int j = 0; j < 3; ++j) {
        int row = (ha * 3 + j) * 16 + r15;
        int si = row * 128 + (k0 ^ ((row & 7) << 3));
        ah[j] = *(const bf16x8*)&lds_hi[si];
        al[j] = *(const bf16x8*)&lds_lo[si];
      }
      __builtin_amdgcn_s_setprio(1);
      #pragma unroll
      for (int jn = 0; jn < 4; ++jn) {
        #pragma unroll
        for (int j = 0; j < 3; ++j) {
          int a = ha * 3 + j;
          acc[a][jn] = MFMA16(ah[j], bh[jn], acc[a][jn], 0, 0, 0);
          acc[a][jn] = MFMA16(al[j], bh[jn], acc[a][jn], 0, 0, 0);
          acc[a][jn] = MFMA16(ah[j], bl[jn], acc[a][jn], 0, 0, 0);
        }
      }
      __builtin_amdgcn_s_setprio(0);
    }
  }
  f32x4 mreg[4];
  #pragma unroll
  for (int jn = 0; jn < 4; ++jn) {
    #pragma unroll
    for (int rg = 0; rg < 4; ++rg) {
      float mm = acc[0][jn][rg];
      #pragma unroll
      for (int a = 1; a < 6; ++a) mm = fminf(mm, acc[a][jn][rg]);
      mreg[jn][rg] = mm;
    }
  }
  __syncthreads();   // all x reads done; planes now dead

  if (wv < 4) {      // u waves: write umin to overlay
    #pragma unroll
    for (int j = 0; j < 4; ++j) {
      int colg = wv * 64 + j * 16 + r15;
      #pragma unroll
      for (int rg = 0; rg < 4; ++rg)
        umin_s[(q * 4 + rg) * OV + colg] = mreg[j][rg];
    }
  }
  __syncthreads();
  if (wv >= 4) {     // v waves: combine in-reg vmin with LDS umin, write out
    #pragma unroll
    for (int j = 0; j < 4; ++j) {
      int g = (wv - 4) * 64 + j * 16 + r15;
      float gbv = gfcn_b[g];
      #pragma unroll
      for (int rg = 0; rg < 4; ++rg) {
        int r = q * 4 + rg;
        out[(size_t)(b0 + r) * 256 + g] =
            fmaxf(umin_s[r * OV + g] + mreg[j][rg] + gbv, 0.f);
      }
    }
  }
}

// ---- fallback: fused (R5 structure, no min-wave bound) ----------------------
__global__ __launch_bounds__(256) void fused_fallback(
    const int* __restrict__ a_ids, const int* __restrict__ b_ids,
    const int* __restrict__ c_ids, const int* __restrict__ event_ids,
    const float* __restrict__ nf, const float* __restrict__ cond,
    const float* __restrict__ text, const float* __restrict__ ent,
    const float* __restrict__ node_b, const float* __restrict__ gfcn_b,
    const short* __restrict__ wsS, const float* __restrict__ bias_af,
    float* __restrict__ out) {
  __shared__ __align__(16) unsigned char smem[49152];
  short* lds_hi = (short*)smem;
  short* lds_lo = (short*)(smem + 24576);
  float* umin_s = (float*)smem;
  float* vmin_s = (float*)(smem + 16640);
  constexpr int OV = 260;

  const int t = threadIdx.x;
  const int wv = t >> 6, lane = t & 63;
  const int r15 = lane & 15, q = lane >> 4;
  const int b0 = blockIdx.x * 16;

  const bf16x8* nwh = (const bf16x8*)(wsS + OFF_NWH);
  const bf16x8* nwl = (const bf16x8*)(wsS + OFF_NWL);
  const bf16x8* wch = (const bf16x8*)(wsS + OFF_WCH);
  const bf16x8* wcl = (const bf16x8*)(wsS + OFF_WCL);
  const bf16x8* gfh = (const bf16x8*)(wsS + OFF_GFH);
  const bf16x8* gfl = (const bf16x8*)(wsS + OFF_GFL);

  const int* pw = (wv == 0) ? a_ids : (wv == 1) ? event_ids
                : (wv == 2) ? b_ids : c_ids;
  int my_id = pw[b0 + r15];
  int eid[4];
  #pragma unroll
  for (int rg = 0; rg < 4; ++rg) eid[rg] = pw[b0 + q * 4 + rg];
  const float* arow = nf + (size_t)my_id * 256 + q * 8;

  float4 avA[8];
  #pragma unroll
  for (int ks = 0; ks < 4; ++ks) {
    avA[2 * ks]     = *(const float4*)(arow + ks * 32);
    avA[2 * ks + 1] = *(const float4*)(arow + ks * 32 + 4);
  }
  #pragma unroll
  for (int j = 0; j < 16; ++j) {
    int i = j * 256 + t;
    int arr = i >> 11, rem = i & 2047, r = rem >> 7, e = rem & 127;
    const float* src = arr ? text : cond;
    float v = src[(size_t)(b0 + r) * 128 + e];
    short h, l;
    split2(v, h, l);
    int row = (4 + arr) * 16 + r;
    int si = row * 128 + (e ^ ((row & 7) << 3));
    lds_hi[si] = h; lds_lo[si] = l;
  }
  {
    f32x4 acc[8];
    #pragma unroll
    for (int n8 = 0; n8 < 8; ++n8) acc[n8] = (f32x4){0.f, 0.f, 0.f, 0.f};
    float4 avB[8];
    #pragma unroll
    for (int ks = 0; ks < 4; ++ks) {
      avB[2 * ks]     = *(const float4*)(arow + (4 + ks) * 32);
      avB[2 * ks + 1] = *(const float4*)(arow + (4 + ks) * 32 + 4);
    }
    #pragma unroll
    for (int ks = 0; ks < 8; ++ks) {
      bf16x8 ah, al;
      {
        float4 v0 = (ks < 4) ? avA[2 * ks] : avB[2 * (ks - 4)];
        float4 v1 = (ks < 4) ? avA[2 * ks + 1] : avB[2 * (ks - 4) + 1];
        #pragma unroll
        for (int j = 0; j < 4; ++j) {
          short h, l;
          split2(v0[j], h, l);
          ah[j] = h; al[j] = l;
          split2(v1[j], h, l);
          ah[4 + j] = h; al[4 + j] = l;
        }
      }
      #pragma unroll
      for (int n8 = 0; n8 < 8; ++n8) {
        bf16x8 bh = nwh[(n8 * 8 + ks) * 64 + lane];
        bf16x8 bl = nwl[(n8 * 8 + ks) * 64 + lane];
        acc[n8] = MFMA16(ah, bh, acc[n8], 0, 0, 0);
        acc[n8] = MFMA16(al, bh, acc[n8], 0, 0, 0);
        acc[n8] = MFMA16(ah, bl, acc[n8], 0, 0, 0);
      }
    }
    float ev[32];
    #pragma unroll
    for (int n8 = 0; n8 < 8; ++n8)
      #pragma unroll
      for (int rg = 0; rg < 4; ++rg)
        ev[n8 * 4 + rg] = ent[(size_t)eid[rg] * 128 + n8 * 16 + r15];
    #pragma unroll
    for (int n8 = 0; n8 < 8; ++n8) {
      int col = n8 * 16 + r15;
      float nb = node_b[col];
      #pragma unroll
      for (int rg = 0; rg < 4; ++rg) {
        float v = ev[n8 * 4 + rg] + fmaxf(acc[n8][rg] + nb, 0.f);
        short h, l; split2(v, h, l);
        int row = wv * 16 + q * 4 + rg;
        int si = row * 128 + (col ^ ((row & 7) << 3));
        lds_hi[si] = h; lds_lo[si] = l;
      }
    }
  }
  __syncthreads();
  {
    f32x4 xacc[6][2];
    #pragma unroll
    for (int a = 0; a < 6; ++a) {
      xacc[a][0] = (f32x4){0.f, 0.f, 0.f, 0.f};
      xacc[a][1] = (f32x4){0.f, 0.f, 0.f, 0.f};
    }
    #pragma unroll
    for (int ks = 0; ks < 4; ++ks) {
      int k0 = ks * 32 + q * 8;
      #pragma unroll
      for (int ha = 0; ha < 2; ++ha) {
        bf16x8 ah[3], al[3];
        #pragma unroll
        for (int j = 0; j < 3; ++j) {
          int row = (ha * 3 + j) * 16 + r15;
          int si = row * 128 + (k0 ^ ((row & 7) << 3));
          ah[j] = *(const bf16x8*)&lds_hi[si];
          al[j] = *(const bf16x8*)&lds_lo[si];
        }
        #pragma unroll
        for (int jn = 0; jn < 2; ++jn) {
          bf16x8 bh = wch[((wv * 2 + jn) * 4 + ks) * 64 + lane];
          bf16x8 bl = wcl[((wv * 2 + jn) * 4 + ks) * 64 + lane];
          #pragma unroll
          for (int j = 0; j < 3; ++j) {
            int a = ha * 3 + j;
            xacc[a][jn] = MFMA16(ah[j], bh, xacc[a][jn], 0, 0, 0);
            xacc[a][jn] = MFMA16(al[j], bh, xacc[a][jn], 0, 0, 0);
            xacc[a][jn] = MFMA16(ah[j], bl, xacc[a][jn], 0, 0, 0);
          }
        }
      }
    }
    __syncthreads();
    #pragma unroll
    for (int a = 0; a < 6; ++a) {
      #pragma unroll
      for (int jn = 0; jn < 2; ++jn) {
        int col = (wv * 2 + jn) * 16 + r15;
        float bv = bias_af[a * 128 + col];
        #pragma unroll
        for (int rg = 0; rg < 4; ++rg) {
          float v = fmaxf(xacc[a][jn][rg] + bv, 0.f);
          short h, l; split2(v, h, l);
          int row = a * 16 + q * 4 + rg;
          int si = row * 128 + (col ^ ((row & 7) << 3));
          lds_hi[si] = h; lds_lo[si] = l;
        }
      }
    }
  }
  __syncthreads();
  f32x4 mreg[8];
  #pragma unroll
  for (int grp = 0; grp < 4; ++grp) {
    f32x4 acc[6][2];
    #pragma unroll
    for (int a = 0; a < 6; ++a) {
      acc[a][0] = (f32x4){0.f, 0.f, 0.f, 0.f};
      acc[a][1] = (f32x4){0.f, 0.f, 0.f, 0.f};
    }
    #pragma unroll
    for (int ks = 0; ks < 4; ++ks) {
      int k0 = ks * 32 + q * 8;
      #pragma unroll
      for (int ha = 0; ha < 2; ++ha) {
        bf16x8 ah[3], al[3];
        #pragma unroll
        for (int j = 0; j < 3; ++j) {
          int row = (ha * 3 + j) * 16 + r15;
          int si = row * 128 + (k0 ^ ((row & 7) << 3));
          ah[j] = *(const bf16x8*)&lds_hi[si];
          al[j] = *(const bf16x8*)&lds_lo[si];
        }
        #pragma unroll
        for (int jn = 0; jn < 2; ++jn) {
          int nfg = wv * 8 + grp * 2 + jn;
          bf16x8 bh = gfh[(nfg * 4 + ks) * 64 + lane];
          bf16x8 bl = gfl[(nfg * 4 + ks) * 64 + lane];
          #pragma unroll
          for (int j = 0; j < 3; ++j) {
            int a = ha * 3 + j;
            acc[a][jn] = MFMA16(ah[j], bh, acc[a][jn], 0, 0, 0);
            acc[a][jn] = MFMA16(al[j], bh, acc[a][jn], 0, 0, 0);
            acc[a][jn] = MFMA16(ah[j], bl, acc[a][jn], 0, 0, 0);
          }
        }
      }
    }
    #pragma unroll
    for (int jn = 0; jn < 2; ++jn) {
      #pragma unroll
      for (int rg = 0; rg < 4; ++rg) {
        float mm = acc[0][jn][rg];
        #pragma unroll
        for (int a = 1; a < 6; ++a) mm = fminf(mm, acc[a][jn][rg]);
        mreg[grp * 2 + jn][rg] = mm;
      }
    }
  }
  __syncthreads();
  {
    float* dst = (wv >= 2) ? vmin_s : umin_s;
    int cbase = (wv & 1) * 128;
    #pragma unroll
    for (int j = 0; j < 8; ++j) {
      int colg = cbase + j * 16 + r15;
      #pragma unroll
      for (int rg = 0; rg < 4; ++rg)
        dst[(q * 4 + rg) * OV + colg] = mreg[j][rg];
    }
  }
  __syncthreads();
  #pragma unroll
  for (int j = 0; j < 16; ++j) {
    int i = j * 256 + t;
    int r = i >> 8, g = i & 255;
    out[(size_t)(b0 + r) * 256 + g] =
        fmaxf(umin_s[r * OV + g] + vmin_s[r * OV + g] + gfcn_b[g], 0.f);
  }
}

extern "C" void kernel_launch(void* const* d_in, const int* in_sizes, int n_in,
                              void* d_out, int out_size, void* d_ws, size_t ws_size,
                              hipStream_t stream) {
  const int* a_ids = (const int*)d_in[0];
  const int* b_ids = (const int*)d_in[1];
  const int* c_ids = (const int*)d_in[2];
  const int* event_ids = (const int*)d_in[3];
  const float* node_features = (const float*)d_in[4];
  const float* cond_rel = (const float*)d_in[5];
  const float* text = (const float*)d_in[6];
  const float* entity_emb = (const float*)d_in[7];
  const float* role_emb = (const float*)d_in[8];
  const float* node_W = (const float*)d_in[9];
  const float* node_b = (const float*)d_in[10];
  const float* conv_W = (const float*)d_in[11];
  const float* conv_b = (const float*)d_in[12];
  const float* bn_gamma = (const float*)d_in[13];
  const float* bn_beta = (const float*)d_in[14];
  const float* bn_mean = (const float*)d_in[15];
  const float* bn_var = (const float*)d_in[16];
  const float* gfcn_W = (const float*)d_in[17];
  const float* gfcn_b = (const float*)d_in[18];
  float* out = (float*)d_out;

  short* wsS = (short*)d_ws;
  float* bias_af = (float*)((char*)d_ws + OFF_BIAS_BYTES);
  const int B = in_sizes[0];   // 32768
  const int NT = B / 16;       // 2048

  setup_kernel<<<452, 256, 0, stream>>>(node_W, conv_W, gfcn_W, role_emb,
                                        conv_b, bn_gamma, bn_beta, bn_mean,
                                        bn_var, wsS, bias_af);
  if (ws_size >= WS_NEED && NT <= NT_MAX) {
    short* vfh = (short*)((char*)d_ws + OFF_VF_BYTES);
    short* vfl = vfh + VF_SH;
    ent_kernel<<<NT, 256, 0, stream>>>(a_ids, b_ids, c_ids, event_ids,
                                       node_features, entity_emb, node_b,
                                       wsS, vfh, vfl);
    head_kernel<<<NT, 512, 0, stream>>>(cond_rel, text, gfcn_b, wsS, bias_af,
                                        vfh, vfl, out);
  } else {
    fused_fallback<<<NT, 256, 0, stream>>>(
        a_ids, b_ids, c_ids, event_ids, node_features, cond_rel, text,
        entity_emb, node_b, gfcn_b, wsS, bias_af, out);
  }
}

// Round 10
// 199.021 us; speedup vs baseline: 2.1195x; 1.0723x over previous
//
#include <hip/hip_runtime.h>
#include <hip/hip_bf16.h>

typedef short bf16x8 __attribute__((ext_vector_type(8)));
typedef float f32x4 __attribute__((ext_vector_type(4)));
#define MFMA16 __builtin_amdgcn_mfma_f32_16x16x32_bf16

// ---- split-bf16 helpers -----------------------------------------------------
__device__ __forceinline__ unsigned short rne_bf16(float f) {
  unsigned u = __builtin_bit_cast(unsigned, f);
  return (unsigned short)((u + 0x7fffu + ((u >> 16) & 1u)) >> 16);
}
__device__ __forceinline__ float bf16f(unsigned short h) {
  unsigned u = ((unsigned)h) << 16;
  return __builtin_bit_cast(float, u);
}
__device__ __forceinline__ void split2(float f, short& h, short& l) {
  unsigned short hh = rne_bf16(f);
  h = (short)hh;
  l = (short)rne_bf16(f - bf16f(hh));
}

// ---- ws layout --------------------------------------------------------------
constexpr int NW_SH = 32768;   // node_W  256x128
constexpr int WC_SH = 16384;   // WcEt    128x128
constexpr int GF_SH = 65536;   // gfcn    128x512
constexpr int OFF_NWH = 0;
constexpr int OFF_NWL = NW_SH;
constexpr int OFF_WCH = 2 * NW_SH;
constexpr int OFF_WCL = 2 * NW_SH + WC_SH;
constexpr int OFF_GFH = 2 * NW_SH + 2 * WC_SH;
constexpr int OFF_GFL = 2 * NW_SH + 2 * WC_SH + GF_SH;
constexpr size_t OFF_BIAS_BYTES = (size_t)(2 * NW_SH + 2 * WC_SH + 2 * GF_SH) * 2; // 458752
constexpr size_t OFF_VF_BYTES = OFF_BIAS_BYTES + 6 * 128 * 4;                      // 461824
constexpr int NT_MAX = 2048;                    // B/16
constexpr int VF_SH = NT_MAX * 4 * 4 * 64 * 8;  // 16777216 shorts per plane
constexpr size_t WS_NEED = OFF_VF_BYTES + (size_t)2 * (size_t)VF_SH * 2;           // ~67.6 MB

// ---- setup: pack weights into MFMA fragment layout (hi/lo bf16 planes) ------
__global__ __launch_bounds__(256) void setup_kernel(
    const float* __restrict__ node_W, const float* __restrict__ conv_W,
    const float* __restrict__ gfcn_W, const float* __restrict__ role_emb,
    const float* __restrict__ conv_b, const float* __restrict__ bn_gamma,
    const float* __restrict__ bn_beta, const float* __restrict__ bn_mean,
    const float* __restrict__ bn_var, short* __restrict__ wsS,
    float* __restrict__ bias_af) {
  int idx = blockIdx.x * 256 + threadIdx.x;
  int stride = gridDim.x * 256;
  for (int i = idx; i < 115456; i += stride) {
    if (i < 114688) {
      int j = i & 7, lane = (i >> 3) & 63;
      int kq = ((lane >> 4) & 3) * 8 + j, n16 = lane & 15;
      float val;
      short *ph, *pl;
      int loc;
      if (i < NW_SH) {
        loc = i;
        int f = i >> 9, kf = f & 7, nfr = f >> 3;
        int k = kf * 32 + kq, n = nfr * 16 + n16;
        val = node_W[k * 128 + n];
        ph = wsS + OFF_NWH; pl = wsS + OFF_NWL;
      } else if (i < NW_SH + WC_SH) {
        loc = i - NW_SH;
        int f = loc >> 9, kf = f & 3, nfr = f >> 2;
        int k = kf * 32 + kq, n = nfr * 16 + n16;
        float s = bn_gamma[n] * rsqrtf(bn_var[n] + 1e-5f);
        val = s * conv_W[n * 256 + 128 + k];     // WcEt[e=k][f=n]
        ph = wsS + OFF_WCH; pl = wsS + OFF_WCL;
      } else {
        loc = i - NW_SH - WC_SH;
        int f = loc >> 9, kf = f & 3, nfr = f >> 2;   // nfr 0..31
        int k = kf * 32 + kq, n = nfr * 16 + n16;     // n 0..511
        val = (n < 256) ? gfcn_W[k * 256 + n]
                        : gfcn_W[(128 + k) * 256 + (n - 256)];
        ph = wsS + OFF_GFH; pl = wsS + OFF_GFL;
      }
      short h, l;
      split2(val, h, l);
      ph[loc] = h; pl[loc] = l;
    } else {
      int loc = i - 114688;
      int a = loc >> 7, fc = loc & 127;
      int role = (a == 5) ? 6 : a;   // ROLES = {0,1,2,3,4,6}
      float s = bn_gamma[fc] * rsqrtf(bn_var[fc] + 1e-5f);
      float dot = 0.f;
      for (int e = 0; e < 128; ++e)
        dot = fmaf(role_emb[role * 128 + e], conv_W[fc * 256 + e], dot);
      bias_af[loc] = s * (dot + conv_b[fc] - bn_mean[fc]) + bn_beta[fc];
    }
  }
}

// ---- kernel A: vals[a] = entity + relu(nf@node_W + node_b) -> ws A-frags ----
// v2: loads pinned early via sched_barrier; per-wave LDS slices; no barriers.
__global__ __launch_bounds__(256) void ent_kernel(
    const int* __restrict__ a_ids, const int* __restrict__ b_ids,
    const int* __restrict__ c_ids, const int* __restrict__ event_ids,
    const float* __restrict__ nf, const float* __restrict__ ent,
    const float* __restrict__ node_b, const short* __restrict__ wsS,
    short* __restrict__ vfh, short* __restrict__ vfl) {
  __shared__ __align__(16) short lhs[4][16 * 128];
  __shared__ __align__(16) short lls[4][16 * 128];
  const int t = threadIdx.x;
  const int wv = t >> 6, lane = t & 63;
  const int r15 = lane & 15, q = lane >> 4;
  const int tile = blockIdx.x;
  const int b0 = tile * 16;

  const bf16x8* nwh = (const bf16x8*)(wsS + OFF_NWH);
  const bf16x8* nwl = (const bf16x8*)(wsS + OFF_NWL);

  // wave wv owns id-column wv; stack order a,event,b,c
  const int* pw = (wv == 0) ? a_ids : (wv == 1) ? event_ids
                : (wv == 2) ? b_ids : c_ids;
  int my_id = pw[b0 + r15];
  int eid[4];
  #pragma unroll
  for (int rg = 0; rg < 4; ++rg) eid[rg] = pw[b0 + q * 4 + rg];
  const float* arow = nf + (size_t)my_id * 256 + q * 8;

  // ---- issue ALL nf gather loads; sched_barrier pins them before any use ----
  float4 av[16];
  #pragma unroll
  for (int ks = 0; ks < 8; ++ks) {
    av[2 * ks]     = *(const float4*)(arow + ks * 32);
    av[2 * ks + 1] = *(const float4*)(arow + ks * 32 + 4);
  }
  __builtin_amdgcn_sched_barrier(0);

  // ---- convert to hi/lo fragments (av dies progressively) -------------------
  bf16x8 Ah[8], Al[8];
  #pragma unroll
  for (int ks = 0; ks < 8; ++ks) {
    #pragma unroll
    for (int j = 0; j < 4; ++j) {
      short h, l;
      split2(av[2 * ks][j], h, l);
      Ah[ks][j] = h; Al[ks][j] = l;
      split2(av[2 * ks + 1][j], h, l);
      Ah[ks][4 + j] = h; Al[ks][4 + j] = l;
    }
  }
  __builtin_amdgcn_sched_barrier(0);

  // ---- issue ent-gather loads now; latency hides under the MFMA loop --------
  float ev[32];
  #pragma unroll
  for (int n8 = 0; n8 < 8; ++n8)
    #pragma unroll
    for (int rg = 0; rg < 4; ++rg)
      ev[n8 * 4 + rg] = ent[(size_t)eid[rg] * 128 + n8 * 16 + r15];
  __builtin_amdgcn_sched_barrier(0);

  // ---- MFMA loop: ks-outer, 8 independent acc chains ------------------------
  f32x4 acc[8];
  #pragma unroll
  for (int n8 = 0; n8 < 8; ++n8) acc[n8] = (f32x4){0.f, 0.f, 0.f, 0.f};
  #pragma unroll
  for (int ks = 0; ks < 8; ++ks) {
    #pragma unroll
    for (int n8 = 0; n8 < 8; ++n8) {
      bf16x8 bh = nwh[(n8 * 8 + ks) * 64 + lane];
      bf16x8 bl = nwl[(n8 * 8 + ks) * 64 + lane];
      acc[n8] = MFMA16(Ah[ks], bh, acc[n8], 0, 0, 0);
      acc[n8] = MFMA16(Al[ks], bh, acc[n8], 0, 0, 0);
      acc[n8] = MFMA16(Ah[ks], bl, acc[n8], 0, 0, 0);
    }
  }

  // ---- epilogue: combine, transpose in per-wave LDS slice (no barriers) -----
  #pragma unroll
  for (int n8 = 0; n8 < 8; ++n8) {
    int col = n8 * 16 + r15;
    float nb = node_b[col];
    #pragma unroll
    for (int rg = 0; rg < 4; ++rg) {
      float v = ev[n8 * 4 + rg] + fmaxf(acc[n8][rg] + nb, 0.f);
      short h, l; split2(v, h, l);
      int rr = q * 4 + rg;                       // row within wave slice
      int si = rr * 128 + (col ^ ((rr & 7) << 3));
      lhs[wv][si] = h; lls[wv][si] = l;
    }
  }
  // frag-layout read from own slice, coalesced ws store (wave-internal RAW,
  // ordered by lgkmcnt — no block barrier needed)
  #pragma unroll
  for (int ks = 0; ks < 4; ++ks) {
    int k0 = ks * 32 + q * 8;
    int si = r15 * 128 + (k0 ^ ((r15 & 7) << 3));
    ((bf16x8*)vfh)[((tile * 4 + wv) * 4 + ks) * 64 + lane] = *(const bf16x8*)&lhs[wv][si];
    ((bf16x8*)vfl)[((tile * 4 + wv) * 4 + ks) * 64 + lane] = *(const bf16x8*)&lls[wv][si];
  }
}

// ---- kernel B: stages C+D, 512 threads / 8 waves, merged-jn D ---------------
__global__ __launch_bounds__(512) void head_kernel(
    const float* __restrict__ cond, const float* __restrict__ text,
    const float* __restrict__ gfcn_b, const short* __restrict__ wsS,
    const float* __restrict__ bias_af, const short* __restrict__ vfh,
    const short* __restrict__ vfl, float* __restrict__ out) {
  __shared__ __align__(16) unsigned char smem[49152];
  short* lds_hi = (short*)smem;                 // 96x128 bf16 hi plane
  short* lds_lo = (short*)(smem + 24576);       // lo plane
  float* umin_s = (float*)smem;                 // overlay after planes dead
  constexpr int OV = 260;

  const int t = threadIdx.x;
  const int wv = t >> 6, lane = t & 63;
  const int r15 = lane & 15, q = lane >> 4;
  const int tile = blockIdx.x;
  const int b0 = tile * 16;

  const bf16x8* wch = (const bf16x8*)(wsS + OFF_WCH);
  const bf16x8* wcl = (const bf16x8*)(wsS + OFF_WCL);
  const bf16x8* gfh = (const bf16x8*)(wsS + OFF_GFH);
  const bf16x8* gfl = (const bf16x8*)(wsS + OFF_GFL);
  const bf16x8* vfh8 = (const bf16x8*)vfh;
  const bf16x8* vfl8 = (const bf16x8*)vfl;

  // ---- Phase 0: stage cond/text rows (a=4,5) into plane rows 64..95 ---------
  #pragma unroll
  for (int j = 0; j < 8; ++j) {
    int i = j * 512 + t;
    int arr = i >> 11, rem = i & 2047, r = rem >> 7, e = rem & 127;
    const float* src = arr ? text : cond;
    float v = src[(size_t)(b0 + r) * 128 + e];
    short h, l;
    split2(v, h, l);
    int row = (4 + arr) * 16 + r;
    int si = row * 128 + (e ^ ((row & 7) << 3));
    lds_hi[si] = h; lds_lo[si] = l;
  }
  __syncthreads();

  // ---- Stage C: x = relu(vals @ WcEt + bias_af); wave owns n-frag wv --------
  {
    f32x4 xacc[6];
    #pragma unroll
    for (int a = 0; a < 6; ++a) xacc[a] = (f32x4){0.f, 0.f, 0.f, 0.f};
    #pragma unroll
    for (int ks = 0; ks < 4; ++ks) {
      int k0 = ks * 32 + q * 8;
      bf16x8 bh = wch[(wv * 4 + ks) * 64 + lane];
      bf16x8 bl = wcl[(wv * 4 + ks) * 64 + lane];
      #pragma unroll
      for (int ha = 0; ha < 2; ++ha) {
        bf16x8 ah[3], al[3];
        #pragma unroll
        for (int j = 0; j < 3; ++j) {
          int a = ha * 3 + j;
          if (a < 4) {
            ah[j] = vfh8[((tile * 4 + a) * 4 + ks) * 64 + lane];
            al[j] = vfl8[((tile * 4 + a) * 4 + ks) * 64 + lane];
          } else {
            int row = a * 16 + r15;
            int si = row * 128 + (k0 ^ ((row & 7) << 3));
            ah[j] = *(const bf16x8*)&lds_hi[si];
            al[j] = *(const bf16x8*)&lds_lo[si];
          }
        }
        __builtin_amdgcn_s_setprio(1);
        #pragma unroll
        for (int j = 0; j < 3; ++j) {
          int a = ha * 3 + j;
          xacc[a] = MFMA16(ah[j], bh, xacc[a], 0, 0, 0);
          xacc[a] = MFMA16(al[j], bh, xacc[a], 0, 0, 0);
          xacc[a] = MFMA16(ah[j], bl, xacc[a], 0, 0, 0);
        }
        __builtin_amdgcn_s_setprio(0);
      }
    }
    __syncthreads();   // all cond/text plane reads done before x overwrites
    #pragma unroll
    for (int a = 0; a < 6; ++a) {
      int col = wv * 16 + r15;
      float bv = bias_af[a * 128 + col];
      #pragma unroll
      for (int rg = 0; rg < 4; ++rg) {
        float v = fmaxf(xacc[a][rg] + bv, 0.f);
        short h, l; split2(v, h, l);
        int row = a * 16 + q * 4 + rg;
        int si = row * 128 + (col ^ ((row & 7) << 3));
        lds_hi[si] = h; lds_lo[si] = l;
      }
    }
  }
  __syncthreads();

  // ---- Stage D: u/v = x @ gfcn; acc[6][4] merged, A-frag reused 12x ---------
  f32x4 acc[6][4];
  #pragma unroll
  for (int a = 0; a < 6; ++a)
    #pragma unroll
    for (int jn = 0; jn < 4; ++jn) acc[a][jn] = (f32x4){0.f, 0.f, 0.f, 0.f};
  #pragma unroll
  for (int ks = 0; ks < 4; ++ks) {
    int k0 = ks * 32 + q * 8;
    bf16x8 bh[4], bl[4];
    #pragma unroll
    for (int jn = 0; jn < 4; ++jn) {
      int nfg = wv * 4 + jn;
      bh[jn] = gfh[(nfg * 4 + ks) * 64 + lane];
      bl[jn] = gfl[(nfg * 4 + ks) * 64 + lane];
    }
    #pragma unroll
    for (int ha = 0; ha < 2; ++ha) {
      bf16x8 ah[3], al[3];
      #pragma unroll
      for (int j = 0; j < 3; ++j) {
        int row = (ha * 3 + j) * 16 + r15;
        int si = row * 128 + (k0 ^ ((row & 7) << 3));
        ah[j] = *(const bf16x8*)&lds_hi[si];
        al[j] = *(const bf16x8*)&lds_lo[si];
      }
      __builtin_amdgcn_s_setprio(1);
      #pragma unroll
      for (int jn = 0; jn < 4; ++jn) {
        #pragma unroll
        for (int j = 0; j < 3; ++j) {
          int a = ha * 3 + j;
          acc[a][jn] = MFMA16(ah[j], bh[jn], acc[a][jn], 0, 0, 0);
          acc[a][jn] = MFMA16(al[j], bh[jn], acc[a][jn], 0, 0, 0);
          acc[a][jn] = MFMA16(ah[j], bl[jn], acc[a][jn], 0, 0, 0);
        }
      }
      __builtin_amdgcn_s_setprio(0);
    }
  }
  f32x4 mreg[4];
  #pragma unroll
  for (int jn = 0; jn < 4; ++jn) {
    #pragma unroll
    for (int rg = 0; rg < 4; ++rg) {
      float mm = acc[0][jn][rg];
      #pragma unroll
      for (int a = 1; a < 6; ++a) mm = fminf(mm, acc[a][jn][rg]);
      mreg[jn][rg] = mm;
    }
  }
  __syncthreads();   // all x reads done; planes now dead

  if (wv < 4) {      // u waves: write umin to overlay
    #pragma unroll
    for (int j = 0; j < 4; ++j) {
      int colg = wv * 64 + j * 16 + r15;
      #pragma unroll
      for (int rg = 0; rg < 4; ++rg)
        umin_s[(q * 4 + rg) * OV + colg] = mreg[j][rg];
    }
  }
  __syncthreads();
  if (wv >= 4) {     // v waves: combine in-reg vmin with LDS umin, write out
    #pragma unroll
    for (int j = 0; j < 4; ++j) {
      int g = (wv - 4) * 64 + j * 16 + r15;
      float gbv = gfcn_b[g];
      #pragma unroll
      for (int rg = 0; rg < 4; ++rg) {
        int r = q * 4 + rg;
        out[(size_t)(b0 + r) * 256 + g] =
            fmaxf(umin_s[r * OV + g] + mreg[j][rg] + gbv, 0.f);
      }
    }
  }
}

// ---- fallback: fused (R5 structure, no min-wave bound) ----------------------
__global__ __launch_bounds__(256) void fused_fallback(
    const int* __restrict__ a_ids, const int* __restrict__ b_ids,
    const int* __restrict__ c_ids, const int* __restrict__ event_ids,
    const float* __restrict__ nf, const float* __restrict__ cond,
    const float* __restrict__ text, const float* __restrict__ ent,
    const float* __restrict__ node_b, const float* __restrict__ gfcn_b,
    const short* __restrict__ wsS, const float* __restrict__ bias_af,
    float* __restrict__ out) {
  __shared__ __align__(16) unsigned char smem[49152];
  short* lds_hi = (short*)smem;
  short* lds_lo = (short*)(smem + 24576);
  float* umin_s = (float*)smem;
  float* vmin_s = (float*)(smem + 16640);
  constexpr int OV = 260;

  const int t = threadIdx.x;
  const int wv = t >> 6, lane = t & 63;
  const int r15 = lane & 15, q = lane >> 4;
  const int b0 = blockIdx.x * 16;

  const bf16x8* nwh = (const bf16x8*)(wsS + OFF_NWH);
  const bf16x8* nwl = (const bf16x8*)(wsS + OFF_NWL);
  const bf16x8* wch = (const bf16x8*)(wsS + OFF_WCH);
  const bf16x8* wcl = (const bf16x8*)(wsS + OFF_WCL);
  const bf16x8* gfh = (const bf16x8*)(wsS + OFF_GFH);
  const bf16x8* gfl = (const bf16x8*)(wsS + OFF_GFL);

  const int* pw = (wv == 0) ? a_ids : (wv == 1) ? event_ids
                : (wv == 2) ? b_ids : c_ids;
  int my_id = pw[b0 + r15];
  int eid[4];
  #pragma unroll
  for (int rg = 0; rg < 4; ++rg) eid[rg] = pw[b0 + q * 4 + rg];
  const float* arow = nf + (size_t)my_id * 256 + q * 8;

  float4 avA[8];
  #pragma unroll
  for (int ks = 0; ks < 4; ++ks) {
    avA[2 * ks]     = *(const float4*)(arow + ks * 32);
    avA[2 * ks + 1] = *(const float4*)(arow + ks * 32 + 4);
  }
  #pragma unroll
  for (int j = 0; j < 16; ++j) {
    int i = j * 256 + t;
    int arr = i >> 11, rem = i & 2047, r = rem >> 7, e = rem & 127;
    const float* src = arr ? text : cond;
    float v = src[(size_t)(b0 + r) * 128 + e];
    short h, l;
    split2(v, h, l);
    int row = (4 + arr) * 16 + r;
    int si = row * 128 + (e ^ ((row & 7) << 3));
    lds_hi[si] = h; lds_lo[si] = l;
  }
  {
    f32x4 acc[8];
    #pragma unroll
    for (int n8 = 0; n8 < 8; ++n8) acc[n8] = (f32x4){0.f, 0.f, 0.f, 0.f};
    float4 avB[8];
    #pragma unroll
    for (int ks = 0; ks < 4; ++ks) {
      avB[2 * ks]     = *(const float4*)(arow + (4 + ks) * 32);
      avB[2 * ks + 1] = *(const float4*)(arow + (4 + ks) * 32 + 4);
    }
    #pragma unroll
    for (int ks = 0; ks < 8; ++ks) {
      bf16x8 ah, al;
      {
        float4 v0 = (ks < 4) ? avA[2 * ks] : avB[2 * (ks - 4)];
        float4 v1 = (ks < 4) ? avA[2 * ks + 1] : avB[2 * (ks - 4) + 1];
        #pragma unroll
        for (int j = 0; j < 4; ++j) {
          short h, l;
          split2(v0[j], h, l);
          ah[j] = h; al[j] = l;
          split2(v1[j], h, l);
          ah[4 + j] = h; al[4 + j] = l;
        }
      }
      #pragma unroll
      for (int n8 = 0; n8 < 8; ++n8) {
        bf16x8 bh = nwh[(n8 * 8 + ks) * 64 + lane];
        bf16x8 bl = nwl[(n8 * 8 + ks) * 64 + lane];
        acc[n8] = MFMA16(ah, bh, acc[n8], 0, 0, 0);
        acc[n8] = MFMA16(al, bh, acc[n8], 0, 0, 0);
        acc[n8] = MFMA16(ah, bl, acc[n8], 0, 0, 0);
      }
    }
    float ev[32];
    #pragma unroll
    for (int n8 = 0; n8 < 8; ++n8)
      #pragma unroll
      for (int rg = 0; rg < 4; ++rg)
        ev[n8 * 4 + rg] = ent[(size_t)eid[rg] * 128 + n8 * 16 + r15];
    #pragma unroll
    for (int n8 = 0; n8 < 8; ++n8) {
      int col = n8 * 16 + r15;
      float nb = node_b[col];
      #pragma unroll
      for (int rg = 0; rg < 4; ++rg) {
        float v = ev[n8 * 4 + rg] + fmaxf(acc[n8][rg] + nb, 0.f);
        short h, l; split2(v, h, l);
        int row = wv * 16 + q * 4 + rg;
        int si = row * 128 + (col ^ ((row & 7) << 3));
        lds_hi[si] = h; lds_lo[si] = l;
      }
    }
  }
  __syncthreads();
  {
    f32x4 xacc[6][2];
    #pragma unroll
    for (int a = 0; a < 6; ++a) {
      xacc[a][0] = (f32x4){0.f, 0.f, 0.f, 0.f};
      xacc[a][1] = (f32x4){0.f, 0.f, 0.f, 0.f};
    }
    #pragma unroll
    for (int ks = 0; ks < 4; ++ks) {
      int k0 = ks * 32 + q * 8;
      #pragma unroll
      for (int ha = 0; ha < 2; ++ha) {
        bf16x8 ah[3], al[3];
        #pragma unroll
        for (int j = 0; j < 3; ++j) {
          int row = (ha * 3 + j) * 16 + r15;
          int si = row * 128 + (k0 ^ ((row & 7) << 3));
          ah[j] = *(const bf16x8*)&lds_hi[si];
          al[j] = *(const bf16x8*)&lds_lo[si];
        }
        #pragma unroll
        for (int jn = 0; jn < 2; ++jn) {
          bf16x8 bh = wch[((wv * 2 + jn) * 4 + ks) * 64 + lane];
          bf16x8 bl = wcl[((wv * 2 + jn) * 4 + ks) * 64 + lane];
          #pragma unroll
          for (int j = 0; j < 3; ++j) {
            int a = ha * 3 + j;
            xacc[a][jn] = MFMA16(ah[j], bh, xacc[a][jn], 0, 0, 0);
            xacc[a][jn] = MFMA16(al[j], bh, xacc[a][jn], 0, 0, 0);
            xacc[a][jn] = MFMA16(ah[j], bl, xacc[a][jn], 0, 0, 0);
          }
        }
      }
    }
    __syncthreads();
    #pragma unroll
    for (int a = 0; a < 6; ++a) {
      #pragma unroll
      for (int jn = 0; jn < 2; ++jn) {
        int col = (wv * 2 + jn) * 16 + r15;
        float bv = bias_af[a * 128 + col];
        #pragma unroll
        for (int rg = 0; rg < 4; ++rg) {
          float v = fmaxf(xacc[a][jn][rg] + bv, 0.f);
          short h, l; split2(v, h, l);
          int row = a * 16 + q * 4 + rg;
          int si = row * 128 + (col ^ ((row & 7) << 3));
          lds_hi[si] = h; lds_lo[si] = l;
        }
      }
    }
  }
  __syncthreads();
  f32x4 mreg[8];
  #pragma unroll
  for (int grp = 0; grp < 4; ++grp) {
    f32x4 acc[6][2];
    #pragma unroll
    for (int a = 0; a < 6; ++a) {
      acc[a][0] = (f32x4){0.f, 0.f, 0.f, 0.f};
      acc[a][1] = (f32x4){0.f, 0.f, 0.f, 0.f};
    }
    #pragma unroll
    for (int ks = 0; ks < 4; ++ks) {
      int k0 = ks * 32 + q * 8;
      #pragma unroll
      for (int ha = 0; ha < 2; ++ha) {
        bf16x8 ah[3], al[3];
        #pragma unroll
        for (int j = 0; j < 3; ++j) {
          int row = (ha * 3 + j) * 16 + r15;
          int si = row * 128 + (k0 ^ ((row & 7) << 3));
          ah[j] = *(const bf16x8*)&lds_hi[si];
          al[j] = *(const bf16x8*)&lds_lo[si];
        }
        #pragma unroll
        for (int jn = 0; jn < 2; ++jn) {
          int nfg = wv * 8 + grp * 2 + jn;
          bf16x8 bh = gfh[(nfg * 4 + ks) * 64 + lane];
          bf16x8 bl = gfl[(nfg * 4 + ks) * 64 + lane];
          #pragma unroll
          for (int j = 0; j < 3; ++j) {
            int a = ha * 3 + j;
            acc[a][jn] = MFMA16(ah[j], bh, acc[a][jn], 0, 0, 0);
            acc[a][jn] = MFMA16(al[j], bh, acc[a][jn], 0, 0, 0);
            acc[a][jn] = MFMA16(ah[j], bl, acc[a][jn], 0, 0, 0);
          }
        }
      }
    }
    #pragma unroll
    for (int jn = 0; jn < 2; ++jn) {
      #pragma unroll
      for (int rg = 0; rg < 4; ++rg) {
        float mm = acc[0][jn][rg];
        #pragma unroll
        for (int a = 1; a < 6; ++a) mm = fminf(mm, acc[a][jn][rg]);
        mreg[grp * 2 + jn][rg] = mm;
      }
    }
  }
  __syncthreads();
  {
    float* dst = (wv >= 2) ? vmin_s : umin_s;
    int cbase = (wv & 1) * 128;
    #pragma unroll
    for (int j = 0; j < 8; ++j) {
      int colg = cbase + j * 16 + r15;
      #pragma unroll
      for (int rg = 0; rg < 4; ++rg)
        dst[(q * 4 + rg) * OV + colg] = mreg[j][rg];
    }
  }
  __syncthreads();
  #pragma unroll
  for (int j = 0; j < 16; ++j) {
    int i = j * 256 + t;
    int r = i >> 8, g = i & 255;
    out[(size_t)(b0 + r) * 256 + g] =
        fmaxf(umin_s[r * OV + g] + vmin_s[r * OV + g] + gfcn_b[g], 0.f);
  }
}

extern "C" void kernel_launch(void* const* d_in, const int* in_sizes, int n_in,
                              void* d_out, int out_size, void* d_ws, size_t ws_size,
                              hipStream_t stream) {
  const int* a_ids = (const int*)d_in[0];
  const int* b_ids = (const int*)d_in[1];
  const int* c_ids = (const int*)d_in[2];
  const int* event_ids = (const int*)d_in[3];
  const float* node_features = (const float*)d_in[4];
  const float* cond_rel = (const float*)d_in[5];
  const float* text = (const float*)d_in[6];
  const float* entity_emb = (const float*)d_in[7];
  const float* role_emb = (const float*)d_in[8];
  const float* node_W = (const float*)d_in[9];
  const float* node_b = (const float*)d_in[10];
  const float* conv_W = (const float*)d_in[11];
  const float* conv_b = (const float*)d_in[12];
  const float* bn_gamma = (const float*)d_in[13];
  const float* bn_beta = (const float*)d_in[14];
  const float* bn_mean = (const float*)d_in[15];
  const float* bn_var = (const float*)d_in[16];
  const float* gfcn_W = (const float*)d_in[17];
  const float* gfcn_b = (const float*)d_in[18];
  float* out = (float*)d_out;

  short* wsS = (short*)d_ws;
  float* bias_af = (float*)((char*)d_ws + OFF_BIAS_BYTES);
  const int B = in_sizes[0];   // 32768
  const int NT = B / 16;       // 2048

  setup_kernel<<<452, 256, 0, stream>>>(node_W, conv_W, gfcn_W, role_emb,
                                        conv_b, bn_gamma, bn_beta, bn_mean,
                                        bn_var, wsS, bias_af);
  if (ws_size >= WS_NEED && NT <= NT_MAX) {
    short* vfh = (short*)((char*)d_ws + OFF_VF_BYTES);
    short* vfl = vfh + VF_SH;
    ent_kernel<<<NT, 256, 0, stream>>>(a_ids, b_ids, c_ids, event_ids,
                                       node_features, entity_emb, node_b,
                                       wsS, vfh, vfl);
    head_kernel<<<NT, 512, 0, stream>>>(cond_rel, text, gfcn_b, wsS, bias_af,
                                        vfh, vfl, out);
  } else {
    fused_fallback<<<NT, 256, 0, stream>>>(
        a_ids, b_ids, c_ids, event_ids, node_features, cond_rel, text,
        entity_emb, node_b, gfcn_b, wsS, bias_af, out);
  }
}